// Round 6
// baseline (241.922 us; speedup 1.0000x reference)
//
#include <hip/hip_runtime.h>
#include <hip/hip_bf16.h>
#include <math.h>

using bf16 = __hip_bfloat16;
typedef __attribute__((ext_vector_type(8))) short bf16x8;
typedef __attribute__((ext_vector_type(4))) float f32x4;
typedef __attribute__((ext_vector_type(4))) unsigned short us4;

#define GAS __attribute__((address_space(1)))
#define LAS __attribute__((address_space(3)))

__device__ __forceinline__ void gload_lds16(const bf16* g, bf16* lds) {
  __builtin_amdgcn_global_load_lds((const GAS void*)g, (LAS void*)lds, 16, 0, 0);
}
__device__ __forceinline__ float b2f(unsigned short u) {
  union { unsigned short s; bf16 b; } x; x.s = u; return __bfloat162float(x.b);
}
__device__ __forceinline__ unsigned short f2b(float f) {
  union { unsigned short s; bf16 b; } x; x.b = __float2bfloat16(f); return x.s;
}

// ---------------- compaction (atomic-free, stable => deterministic) ----------------
__global__ __launch_bounds__(256) void hist_k(const int* __restrict__ lab,
                                              int* __restrict__ blockHist) {
  const int blk = blockIdx.x, t = threadIdx.x;
  const int lane = t & 63, w = t >> 6;
  const int d = lab[blk * 256 + t];
  __shared__ int wc[4][3];
#pragma unroll
  for (int dd = 0; dd < 3; ++dd) {
    unsigned long long m = __ballot(d == dd);
    if (lane == 0) wc[w][dd] = __popcll(m);
  }
  __syncthreads();
  if (t < 3) blockHist[blk * 3 + t] = wc[0][t] + wc[1][t] + wc[2][t] + wc[3][t];
}

__global__ __launch_bounds__(256) void scan_k(const int* __restrict__ blockHist,
                                              int* __restrict__ blockOff,
                                              int* __restrict__ meta) {
  __shared__ int h[64][3];
  __shared__ int tot[3];
  const int t = threadIdx.x;
  if (t < 192) h[t / 3][t % 3] = blockHist[t];
  __syncthreads();
  if (t < 3) {
    int s = 0;
    for (int b = 0; b < 64; ++b) { int v = h[b][t]; h[b][t] = s; s += v; }
    tot[t] = s;
    meta[t] = s;
  }
  __syncthreads();
  if (t == 0) { meta[4] = 0; meta[5] = tot[0]; meta[6] = tot[0] + tot[1]; }
  if (t < 192) {
    int b = t / 3, d = t % 3;
    int base = (d == 0) ? 0 : (d == 1 ? tot[0] : tot[0] + tot[1]);
    blockOff[t] = base + h[b][d];
  }
}

__global__ __launch_bounds__(256) void scatter2_k(const int* __restrict__ lab,
                                                  const int* __restrict__ blockOff,
                                                  int* __restrict__ perm) {
  const int blk = blockIdx.x, t = threadIdx.x;
  const int lane = t & 63, w = t >> 6;
  const int i = blk * 256 + t;
  const int d = lab[i];
  __shared__ int wc[4][3];
  unsigned long long mymask = 0;
#pragma unroll
  for (int dd = 0; dd < 3; ++dd) {
    unsigned long long m = __ballot(d == dd);
    if (lane == 0) wc[w][dd] = __popcll(m);
    if (dd == d) mymask = m;
  }
  __syncthreads();
  int woff = 0;
  for (int ww = 0; ww < w; ++ww) woff += wc[ww][d];
  const unsigned long long lt = ((unsigned long long)1 << lane) - 1;
  const int rank = blockOff[blk * 3 + d] + woff + __popcll(mymask & lt);
  perm[rank] = i;
}

// ---------------- dtype conversions ----------------
__global__ __launch_bounds__(256) void cvt_bf16_k(const float* __restrict__ in,
                                                  bf16* __restrict__ out, int n4) {
  int i = blockIdx.x * 256 + threadIdx.x;
  if (i >= n4) return;
  float4 v = ((const float4*)in)[i];
  bf16 t[4] = {__float2bfloat16(v.x), __float2bfloat16(v.y),
               __float2bfloat16(v.z), __float2bfloat16(v.w)};
  ((us4*)out)[i] = *(const us4*)t;
}

__global__ __launch_bounds__(256) void cvt_wt_k(const float* __restrict__ W1,
                                                const float* __restrict__ W2,
                                                const float* __restrict__ txt,
                                                bf16* __restrict__ W1T,
                                                bf16* __restrict__ W2T,
                                                bf16* __restrict__ Tb) {
  int i = blockIdx.x * 256 + threadIdx.x;
  const int n1 = 3 * 256 * 1024;
  const int n2 = n1 + 3 * 1024 * 256;
  const int n3 = n2 + 1536 * 1024;
  if (i < n1) {
    int d = i >> 18, rem = i & 262143;
    int r = rem >> 10, k = rem & 1023;
    W1T[i] = __float2bfloat16(W1[(size_t)d * 262144 + (size_t)k * 256 + r]);
  } else if (i < n2) {
    int j = i - n1;
    int d = j >> 18, rem = j & 262143;
    int n = rem >> 8, k = rem & 255;
    W2T[j] = __float2bfloat16(W2[(size_t)d * 262144 + (size_t)k * 1024 + n]);
  } else if (i < n3) {
    int j = i - n2;
    Tb[j] = (j < 1380 * 1024) ? __float2bfloat16(txt[j]) : __float2bfloat16(0.f);
  }
}

// ---------------- 128^2 2-phase GEMM (verified) for GEMM1/GEMM2 ----------------
template <bool SEG, bool GATHER_A, bool SCATTER_C, bool RELU, bool C_BF16, bool SCALE>
__global__ __launch_bounds__(256) void gemm_bt(
    const bf16* __restrict__ A, const bf16* __restrict__ BT, void* __restrict__ Cv,
    const int* __restrict__ perm, const int* __restrict__ meta, int Mfull, int N,
    int K, int ldc, int Nvalid, const float* __restrict__ scale_ptr) {
  int cnt = Mfull, base = 0;
  if (SEG) {
    int dom = blockIdx.z;
    cnt = meta[dom];
    base = meta[4 + dom];
    BT += (size_t)dom * N * K;
  }
  const int m0 = blockIdx.x * 128;
  if (m0 >= cnt) return;
  const int n0 = blockIdx.y * 128;

  __shared__ bf16 sA[2][128][32];
  __shared__ bf16 sB[2][128][32];

  const int tid = threadIdx.x;
  const int wid = tid >> 6;
  const int lane = tid & 63;

  const int srow = (wid << 4) + (lane >> 2);
  const int skoff = (lane & 3) << 3;

  int p0 = m0 + srow;       if (p0 > cnt - 1) p0 = cnt - 1;
  int p1 = m0 + srow + 64;  if (p1 > cnt - 1) p1 = cnt - 1;
  long ar0, ar1;
  if (GATHER_A) { ar0 = perm[base + p0]; ar1 = perm[base + p1]; }
  else          { ar0 = base + p0;       ar1 = base + p1; }
  const bf16* a0 = A + (size_t)ar0 * K + skoff;
  const bf16* a1 = A + (size_t)ar1 * K + skoff;
  const bf16* b0 = BT + (size_t)(n0 + srow) * K + skoff;
  const bf16* b1 = BT + (size_t)(n0 + srow + 64) * K + skoff;

  const int fr = lane & 15;
  const int fq = lane >> 4;

  f32x4 acc[4][4];
#pragma unroll
  for (int m = 0; m < 4; ++m)
#pragma unroll
    for (int n = 0; n < 4; ++n) acc[m][n] = (f32x4){0.f, 0.f, 0.f, 0.f};

  const int nk = K >> 5;
  auto stage = [&](int buf, int kt) {
    gload_lds16(a0 + kt * 32, &sA[buf][wid * 16][0]);
    gload_lds16(a1 + kt * 32, &sA[buf][wid * 16 + 64][0]);
    gload_lds16(b0 + kt * 32, &sB[buf][wid * 16][0]);
    gload_lds16(b1 + kt * 32, &sB[buf][wid * 16 + 64][0]);
  };

  stage(0, 0);
  __syncthreads();
  const int wr = wid >> 1, wc = wid & 1;
  for (int kt = 0; kt < nk; ++kt) {
    const int cur = kt & 1;
    if (kt + 1 < nk) stage(cur ^ 1, kt + 1);
    bf16x8 af[4], bfr[4];
#pragma unroll
    for (int m = 0; m < 4; ++m)
      af[m] = *(const bf16x8*)&sA[cur][wr * 64 + m * 16 + fr][fq * 8];
#pragma unroll
    for (int n = 0; n < 4; ++n)
      bfr[n] = *(const bf16x8*)&sB[cur][wc * 64 + n * 16 + fr][fq * 8];
#pragma unroll
    for (int m = 0; m < 4; ++m)
#pragma unroll
      for (int n = 0; n < 4; ++n)
        acc[m][n] = __builtin_amdgcn_mfma_f32_16x16x32_bf16(af[m], bfr[n], acc[m][n], 0, 0, 0);
    __syncthreads();
  }

  float s = 1.f;
  if (SCALE) s = expf(*scale_ptr);
#pragma unroll
  for (int m = 0; m < 4; ++m) {
#pragma unroll
    for (int r = 0; r < 4; ++r) {
      const int p = m0 + wr * 64 + m * 16 + fq * 4 + r;
      if (p < cnt) {
        size_t crow;
        if (SCATTER_C) crow = perm[base + p];
        else if (SEG)  crow = base + p;
        else           crow = p;
#pragma unroll
        for (int n = 0; n < 4; ++n) {
          const int col = n0 + wc * 64 + n * 16 + fr;
          if (col < Nvalid) {
            float v = acc[m][n][r];
            if (RELU) v = fmaxf(v, 0.f);
            v *= s;
            if (C_BF16) ((bf16*)Cv)[crow * (size_t)ldc + col] = __float2bfloat16(v);
            else        ((float*)Cv)[crow * (size_t)ldc + col] = v;
          }
        }
      }
    }
  }
}

// ============ V1: gemm3_t8 — m201-geometry 256x256, BK=64, wave 128x64, 16-MFMA phases ============
// grid 64x6 = 384 (1.5 rounds). mb-major XCD swizzle: XCD x owns mb in [8x,8x+8) x all nb
// (A 8-panel working set ~4MB -> L2-resident per XCD; B via L3).
__global__ __launch_bounds__(512, 2) void gemm3_t8(
    const bf16* __restrict__ A, const bf16* __restrict__ BT,
    float* __restrict__ C, const float* __restrict__ scale_ptr) {
  extern __shared__ bf16 smem[];
  bf16* sA0 = smem;            // [2][256][64]
  bf16* sB0 = smem + 32768;    // [2][256][64]

  const int tid = threadIdx.x;
  const int lane = tid & 63, wid = tid >> 6;
  const int wr = wid >> 2, wc = wid & 3;     // 2x4; wave C = 128x64
  const int fr = lane & 15, fq = lane >> 4;

  const int bid = blockIdx.x;
  const int x = bid & 7, seq = bid >> 3;     // seq 0..47
  const int mb = x * 8 + seq / 6, nb = seq % 6;
  const int m0 = mb << 8, n0 = nb << 8;

  auto STAGE = [&](int t, int isB, int half) {   // one 16KB half-tile, 2 loads/thread
    const bf16* G = isB ? BT : A;
    bf16* dstb = (isB ? sB0 : sA0) + ((t & 1) << 14) + (half << 13);
    const int row0 = (isB ? n0 : m0) + (half << 7);
    const int koff = t << 6;
#pragma unroll
    for (int L = 0; L < 2; ++L) {
      const int idx = (L << 9) + tid;
      const int r = idx >> 3, c = idx & 7;
      gload_lds16(G + (size_t)(row0 + r) * 1024 + koff + ((c ^ (r & 7)) << 3),
                  dstb + ((idx & ~63) << 3));
    }
  };
  auto LDA = [&](int slot, int kk, bf16x8* dst) {
    const bf16* base = sA0 + (slot << 14);
#pragma unroll
    for (int m = 0; m < 8; ++m) {
      const int row = (wr << 7) + (m << 4) + fr;
      dst[m] = *(const bf16x8*)(base + (row << 6) + ((((kk << 2) + fq) ^ (fr & 7)) << 3));
    }
  };
  auto LDB2 = [&](int slot, int kk, int nbase, bf16x8* dst) {
    const bf16* base = sB0 + (slot << 14);
#pragma unroll
    for (int n = 0; n < 2; ++n) {
      const int row = (wc << 6) + ((nbase + n) << 4) + fr;
      dst[n] = *(const bf16x8*)(base + (row << 6) + ((((kk << 2) + fq) ^ (fr & 7)) << 3));
    }
  };

  f32x4 acc[8][4];
#pragma unroll
  for (int m = 0; m < 8; ++m)
#pragma unroll
    for (int n = 0; n < 4; ++n) acc[m][n] = (f32x4){0.f, 0.f, 0.f, 0.f};

#define BAR __builtin_amdgcn_s_barrier()
#define MM16(AF, BF0, BF1, N0)                                                 \
  _Pragma("unroll") for (int m = 0; m < 8; ++m) {                              \
    acc[m][N0]     = __builtin_amdgcn_mfma_f32_16x16x32_bf16(AF[m], BF0, acc[m][N0], 0, 0, 0);     \
    acc[m][N0 + 1] = __builtin_amdgcn_mfma_f32_16x16x32_bf16(AF[m], BF1, acc[m][N0 + 1], 0, 0, 0); \
  }

  // prologue: tiles 0,1 fully staged (8 loads each); drain tile0, keep tile1 flying
  STAGE(0, 0, 0); STAGE(0, 0, 1); STAGE(0, 1, 0); STAGE(0, 1, 1);
  STAGE(1, 0, 0); STAGE(1, 0, 1); STAGE(1, 1, 0); STAGE(1, 1, 1);
  asm volatile("s_waitcnt vmcnt(8)" ::: "memory");
  BAR;

  const int nt = 16;
  for (int t = 0; t < nt; ++t) {
    const int s = t & 1;
    bf16x8 a0[8], a1[8], b0[4], b1[4];
    // ph0: A(kk0) + B(kk0,n01)
    LDA(s, 0, a0); LDB2(s, 0, 0, &b0[0]);
    BAR;
    __builtin_amdgcn_s_setprio(1);
    MM16(a0, b0[0], b0[1], 0);
    __builtin_amdgcn_s_setprio(0);
    BAR;
    // ph1: B(kk0,n23) + A(kk1)
    LDB2(s, 0, 2, &b0[2]); LDA(s, 1, a1);
    BAR;
    __builtin_amdgcn_s_setprio(1);
    MM16(a0, b0[2], b0[3], 2);
    __builtin_amdgcn_s_setprio(0);
    BAR;
    // ph2: B(kk1) all
    LDB2(s, 1, 0, &b1[0]); LDB2(s, 1, 2, &b1[2]);
    BAR;
    __builtin_amdgcn_s_setprio(1);
    MM16(a1, b1[0], b1[1], 0);
    __builtin_amdgcn_s_setprio(0);
    BAR;
    // ph3: stage tile t+2 into slot s (safe: all slot-s ds_reads serviced), counted vmcnt
    if (t + 2 < nt) {
      asm volatile("s_waitcnt lgkmcnt(0)" ::: "memory");
      STAGE(t + 2, 0, 0); STAGE(t + 2, 0, 1); STAGE(t + 2, 1, 0); STAGE(t + 2, 1, 1);
      asm volatile("s_waitcnt vmcnt(8)" ::: "memory");   // drain tile t+1, keep t+2
    } else if (t + 1 < nt) {
      asm volatile("s_waitcnt vmcnt(0)" ::: "memory");
    }
    BAR;
    __builtin_amdgcn_s_setprio(1);
    MM16(a1, b1[2], b1[3], 2);
    __builtin_amdgcn_s_setprio(0);
    BAR;
  }
#undef MM16
#undef BAR

  const float sc = expf(*scale_ptr);
#pragma unroll
  for (int m = 0; m < 8; ++m) {
    const int grow = m0 + (wr << 7) + (m << 4) + (fq << 2);
#pragma unroll
    for (int r = 0; r < 4; ++r) {
#pragma unroll
      for (int n = 0; n < 4; ++n) {
        const int gcol = n0 + (wc << 6) + (n << 4) + fr;
        if (gcol < 1380) C[(size_t)(grow + r) * 1380 + gcol] = acc[m][n][r] * sc;
      }
    }
  }
}

// ============ V2: gemm3_occ — 128x192, BK=64, 4 waves, 80KB LDS -> 2 blocks/CU ============
// grid 128x8 = 1024 = exactly 2 packed rounds of 512 block-slots. m97 2-phase loop;
// cross-block TLP hides the barrier drain. mb-major XCD swizzle.
__global__ __launch_bounds__(256, 2) void gemm3_occ(
    const bf16* __restrict__ A, const bf16* __restrict__ BT,
    float* __restrict__ C, const float* __restrict__ scale_ptr) {
  extern __shared__ bf16 smem[];
  bf16* sA0 = smem;            // [2][128][64] = 32KB
  bf16* sB0 = smem + 16384;    // [2][192][64] = 48KB

  const int tid = threadIdx.x;
  const int lane = tid & 63, wid = tid >> 6;
  const int wr = wid >> 1, wc = wid & 1;     // 2x2; wave C = 64x96
  const int fr = lane & 15, fq = lane >> 4;

  const int bid = blockIdx.x;
  const int x = bid & 7, seq = bid >> 3;     // seq 0..127
  const int mb = x * 16 + (seq >> 3), nb = seq & 7;
  const int m0 = mb << 7, n0 = nb * 192;

  auto STAGE = [&](int t) {     // A 4 + B 6 loads/thread
    const int s = t & 1, koff = t << 6;
    bf16* da = sA0 + (s << 13);
#pragma unroll
    for (int L = 0; L < 4; ++L) {
      const int idx = (L << 8) + tid;
      const int r = idx >> 3, c = idx & 7;
      gload_lds16(A + (size_t)(m0 + r) * 1024 + koff + ((c ^ (r & 7)) << 3),
                  da + ((idx & ~63) << 3));
    }
    bf16* db = sB0 + s * 12288;
#pragma unroll
    for (int L = 0; L < 6; ++L) {
      const int idx = (L << 8) + tid;
      const int r = idx >> 3, c = idx & 7;
      gload_lds16(BT + (size_t)(n0 + r) * 1024 + koff + ((c ^ (r & 7)) << 3),
                  db + ((idx & ~63) << 3));
    }
  };
  auto LDA = [&](int s, int kk, bf16x8* dst) {
    const bf16* base = sA0 + (s << 13);
#pragma unroll
    for (int m = 0; m < 4; ++m) {
      const int row = (wr << 6) + (m << 4) + fr;
      dst[m] = *(const bf16x8*)(base + (row << 6) + ((((kk << 2) + fq) ^ (fr & 7)) << 3));
    }
  };
  auto LDB = [&](int s, int kk, bf16x8* dst) {
    const bf16* base = sB0 + s * 12288;
#pragma unroll
    for (int n = 0; n < 6; ++n) {
      const int row = wc * 96 + (n << 4) + fr;
      dst[n] = *(const bf16x8*)(base + (row << 6) + ((((kk << 2) + fq) ^ (fr & 7)) << 3));
    }
  };

  f32x4 acc[4][6];
#pragma unroll
  for (int m = 0; m < 4; ++m)
#pragma unroll
    for (int n = 0; n < 6; ++n) acc[m][n] = (f32x4){0.f, 0.f, 0.f, 0.f};

  STAGE(0);
  __syncthreads();
  const int nt = 16;
  for (int t = 0; t < nt; ++t) {
    const int s = t & 1;
    if (t + 1 < nt) STAGE(t + 1);
    bf16x8 a0[4], a1[4], b0[6], b1[6];
    LDA(s, 0, a0); LDB(s, 0, b0);
    LDA(s, 1, a1); LDB(s, 1, b1);
#pragma unroll
    for (int m = 0; m < 4; ++m)
#pragma unroll
      for (int n = 0; n < 6; ++n)
        acc[m][n] = __builtin_amdgcn_mfma_f32_16x16x32_bf16(a0[m], b0[n], acc[m][n], 0, 0, 0);
#pragma unroll
    for (int m = 0; m < 4; ++m)
#pragma unroll
      for (int n = 0; n < 6; ++n)
        acc[m][n] = __builtin_amdgcn_mfma_f32_16x16x32_bf16(a1[m], b1[n], acc[m][n], 0, 0, 0);
    __syncthreads();
  }

  const float sc = expf(*scale_ptr);
#pragma unroll
  for (int m = 0; m < 4; ++m) {
    const int grow = m0 + (wr << 6) + (m << 4) + (fq << 2);
#pragma unroll
    for (int r = 0; r < 4; ++r) {
#pragma unroll
      for (int n = 0; n < 6; ++n) {
        const int gcol = n0 + wc * 96 + (n << 4) + fr;
        if (gcol < 1380) C[(size_t)(grow + r) * 1380 + gcol] = acc[m][n][r] * sc;
      }
    }
  }
}

// ------- fused = normalize(0.2*a + 0.8*x), in place over F; vectorized loads -------
template <bool XB>
__global__ __launch_bounds__(256) void fuse_norm_k(const float* __restrict__ x,
                                                   const bf16* __restrict__ xb,
                                                   bf16* __restrict__ F) {
  const int row = blockIdx.x;
  const int t = threadIdx.x;
  const size_t roff = (size_t)row * 1024;
  us4 av = ((const us4*)(F + roff))[t];
  float xv[4];
  if (XB) {
    us4 xq = ((const us4*)(xb + roff))[t];
#pragma unroll
    for (int j = 0; j < 4; ++j) xv[j] = b2f(xq[j]);
  } else {
    float4 xf = ((const float4*)(x + roff))[t];
    xv[0] = xf.x; xv[1] = xf.y; xv[2] = xf.z; xv[3] = xf.w;
  }
  float f[4];
  float ss = 0.f;
#pragma unroll
  for (int j = 0; j < 4; ++j) {
    f[j] = 0.2f * b2f(av[j]) + 0.8f * xv[j];
    ss += f[j] * f[j];
  }
#pragma unroll
  for (int o = 32; o > 0; o >>= 1) ss += __shfl_down(ss, o);
  __shared__ float sred[4];
  if ((t & 63) == 0) sred[t >> 6] = ss;
  __syncthreads();
  const float rinv = 1.0f / sqrtf(sred[0] + sred[1] + sred[2] + sred[3]);
  us4 ov;
#pragma unroll
  for (int j = 0; j < 4; ++j) ov[j] = f2b(f[j] * rinv);
  ((us4*)(F + roff))[t] = ov;
}

extern "C" void kernel_launch(void* const* d_in, const int* in_sizes, int n_in,
                              void* d_out, int out_size, void* d_ws, size_t ws_size,
                              hipStream_t stream) {
  (void)in_sizes; (void)n_in; (void)out_size;
  const float* x    = (const float*)d_in[0];
  const int*   lab  = (const int*)d_in[1];
  const float* W1   = (const float*)d_in[2];
  const float* W2   = (const float*)d_in[3];
  const float* text = (const float*)d_in[4];
  const float* lsc  = (const float*)d_in[5];
  float* out = (float*)d_out;

  const int B = 16384, D = 1024, R = 256, NTP = 1536;

  char* p = (char*)d_ws;
  auto carve = [&](size_t bytes) {
    char* r = p;
    p += (bytes + 255) & ~(size_t)255;
    return r;
  };
  int*  meta  = (int*)carve(64);
  int*  bhist = (int*)carve(64 * 3 * 4);
  int*  boff  = (int*)carve(64 * 3 * 4);
  int*  perm  = (int*)carve((size_t)B * 4);
  bf16* Xb    = (bf16*)carve((size_t)B * D * 2);
  bf16* W1T   = (bf16*)carve((size_t)3 * R * D * 2);
  bf16* W2T   = (bf16*)carve((size_t)3 * D * R * 2);
  bf16* Tb    = (bf16*)carve((size_t)NTP * D * 2);
  bf16* H     = (bf16*)carve((size_t)B * R * 2);
  bf16* Fb    = (bf16*)carve((size_t)B * D * 2);
  const bool bigws = (size_t)(p - (char*)d_ws) <= ws_size;
  if (!bigws) Fb = Xb;

  hist_k<<<B / 256, 256, 0, stream>>>(lab, bhist);
  scan_k<<<1, 256, 0, stream>>>(bhist, boff, meta);
  scatter2_k<<<B / 256, 256, 0, stream>>>(lab, boff, perm);

  cvt_bf16_k<<<(B * D / 4 + 255) / 256, 256, 0, stream>>>(x, Xb, B * D / 4);
  {
    const int total = 3 * R * D + 3 * D * R + NTP * D;
    cvt_wt_k<<<(total + 255) / 256, 256, 0, stream>>>(W1, W2, text, W1T, W2T, Tb);
  }

  dim3 g1(128, 2, 3);
  gemm_bt<true, true, false, true, true, false><<<g1, 256, 0, stream>>>(
      Xb, W1T, H, perm, meta, B, R, D, R, R, nullptr);
  dim3 g2(128, 8, 3);
  gemm_bt<true, false, true, true, true, false><<<g2, 256, 0, stream>>>(
      H, W2T, Fb, perm, meta, B, D, R, D, D, nullptr);
  if (bigws) fuse_norm_k<true><<<B, 256, 0, stream>>>(x, Xb, Fb);
  else       fuse_norm_k<false><<<B, 256, 0, stream>>>(x, nullptr, Fb);

  // --- A/B measurement: V1 (extra, overwritten) then V2 (final output) ---
  gemm3_t8<<<384, 512, 131072, stream>>>(Fb, Tb, out, lsc);
  gemm3_occ<<<1024, 256, 81920, stream>>>(Fb, Tb, out, lsc);
}

// Round 7
// 170.246 us; speedup vs baseline: 1.4210x; 1.4210x over previous
//
#include <hip/hip_runtime.h>
#include <hip/hip_bf16.h>
#include <math.h>

using bf16 = __hip_bfloat16;
typedef __attribute__((ext_vector_type(8))) short bf16x8;
typedef __attribute__((ext_vector_type(4))) float f32x4;
typedef __attribute__((ext_vector_type(4))) unsigned short us4;

#define GAS __attribute__((address_space(1)))
#define LAS __attribute__((address_space(3)))

__device__ __forceinline__ void gload_lds16(const bf16* g, bf16* lds) {
  __builtin_amdgcn_global_load_lds((const GAS void*)g, (LAS void*)lds, 16, 0, 0);
}
__device__ __forceinline__ float b2f(unsigned short u) {
  union { unsigned short s; bf16 b; } x; x.s = u; return __bfloat162float(x.b);
}
__device__ __forceinline__ unsigned short f2b(float f) {
  union { unsigned short s; bf16 b; } x; x.b = __float2bfloat16(f); return x.s;
}

// ---------------- compaction (atomic-free, stable => deterministic) ----------------
__global__ __launch_bounds__(256) void hist_k(const int* __restrict__ lab,
                                              int* __restrict__ blockHist) {
  const int blk = blockIdx.x, t = threadIdx.x;
  const int lane = t & 63, w = t >> 6;
  const int d = lab[blk * 256 + t];
  __shared__ int wc[4][3];
#pragma unroll
  for (int dd = 0; dd < 3; ++dd) {
    unsigned long long m = __ballot(d == dd);
    if (lane == 0) wc[w][dd] = __popcll(m);
  }
  __syncthreads();
  if (t < 3) blockHist[blk * 3 + t] = wc[0][t] + wc[1][t] + wc[2][t] + wc[3][t];
}

__global__ __launch_bounds__(256) void scan_k(const int* __restrict__ blockHist,
                                              int* __restrict__ blockOff,
                                              int* __restrict__ meta) {
  __shared__ int h[64][3];
  __shared__ int tot[3];
  const int t = threadIdx.x;
  if (t < 192) h[t / 3][t % 3] = blockHist[t];
  __syncthreads();
  if (t < 3) {
    int s = 0;
    for (int b = 0; b < 64; ++b) { int v = h[b][t]; h[b][t] = s; s += v; }
    tot[t] = s;
    meta[t] = s;
  }
  __syncthreads();
  if (t == 0) { meta[4] = 0; meta[5] = tot[0]; meta[6] = tot[0] + tot[1]; }
  if (t < 192) {
    int b = t / 3, d = t % 3;
    int base = (d == 0) ? 0 : (d == 1 ? tot[0] : tot[0] + tot[1]);
    blockOff[t] = base + h[b][d];
  }
}

__global__ __launch_bounds__(256) void scatter2_k(const int* __restrict__ lab,
                                                  const int* __restrict__ blockOff,
                                                  int* __restrict__ perm) {
  const int blk = blockIdx.x, t = threadIdx.x;
  const int lane = t & 63, w = t >> 6;
  const int i = blk * 256 + t;
  const int d = lab[i];
  __shared__ int wc[4][3];
  unsigned long long mymask = 0;
#pragma unroll
  for (int dd = 0; dd < 3; ++dd) {
    unsigned long long m = __ballot(d == dd);
    if (lane == 0) wc[w][dd] = __popcll(m);
    if (dd == d) mymask = m;
  }
  __syncthreads();
  int woff = 0;
  for (int ww = 0; ww < w; ++ww) woff += wc[ww][d];
  const unsigned long long lt = ((unsigned long long)1 << lane) - 1;
  const int rank = blockOff[blk * 3 + d] + woff + __popcll(mymask & lt);
  perm[rank] = i;
}

// ---------------- dtype conversions ----------------
__global__ __launch_bounds__(256) void cvt_bf16_k(const float* __restrict__ in,
                                                  bf16* __restrict__ out, int n4) {
  int i = blockIdx.x * 256 + threadIdx.x;
  if (i >= n4) return;
  float4 v = ((const float4*)in)[i];
  bf16 t[4] = {__float2bfloat16(v.x), __float2bfloat16(v.y),
               __float2bfloat16(v.z), __float2bfloat16(v.w)};
  ((us4*)out)[i] = *(const us4*)t;
}

__global__ __launch_bounds__(256) void cvt_wt_k(const float* __restrict__ W1,
                                                const float* __restrict__ W2,
                                                const float* __restrict__ txt,
                                                bf16* __restrict__ W1T,
                                                bf16* __restrict__ W2T,
                                                bf16* __restrict__ Tb) {
  int i = blockIdx.x * 256 + threadIdx.x;
  const int n1 = 3 * 256 * 1024;
  const int n2 = n1 + 3 * 1024 * 256;
  const int n3 = n2 + 1536 * 1024;
  if (i < n1) {
    int d = i >> 18, rem = i & 262143;
    int r = rem >> 10, k = rem & 1023;
    W1T[i] = __float2bfloat16(W1[(size_t)d * 262144 + (size_t)k * 256 + r]);
  } else if (i < n2) {
    int j = i - n1;
    int d = j >> 18, rem = j & 262143;
    int n = rem >> 8, k = rem & 255;
    W2T[j] = __float2bfloat16(W2[(size_t)d * 262144 + (size_t)k * 1024 + n]);
  } else if (i < n3) {
    int j = i - n2;
    Tb[j] = (j < 1380 * 1024) ? __float2bfloat16(txt[j]) : __float2bfloat16(0.f);
  }
}

// ---------------- 128^2 2-phase GEMM (verified) for GEMM1/GEMM2 ----------------
template <bool SEG, bool GATHER_A, bool SCATTER_C, bool RELU, bool C_BF16, bool SCALE>
__global__ __launch_bounds__(256) void gemm_bt(
    const bf16* __restrict__ A, const bf16* __restrict__ BT, void* __restrict__ Cv,
    const int* __restrict__ perm, const int* __restrict__ meta, int Mfull, int N,
    int K, int ldc, int Nvalid, const float* __restrict__ scale_ptr) {
  int cnt = Mfull, base = 0;
  if (SEG) {
    int dom = blockIdx.z;
    cnt = meta[dom];
    base = meta[4 + dom];
    BT += (size_t)dom * N * K;
  }
  const int m0 = blockIdx.x * 128;
  if (m0 >= cnt) return;
  const int n0 = blockIdx.y * 128;

  __shared__ bf16 sA[2][128][32];
  __shared__ bf16 sB[2][128][32];

  const int tid = threadIdx.x;
  const int wid = tid >> 6;
  const int lane = tid & 63;

  const int srow = (wid << 4) + (lane >> 2);
  const int skoff = (lane & 3) << 3;

  int p0 = m0 + srow;       if (p0 > cnt - 1) p0 = cnt - 1;
  int p1 = m0 + srow + 64;  if (p1 > cnt - 1) p1 = cnt - 1;
  long ar0, ar1;
  if (GATHER_A) { ar0 = perm[base + p0]; ar1 = perm[base + p1]; }
  else          { ar0 = base + p0;       ar1 = base + p1; }
  const bf16* a0 = A + (size_t)ar0 * K + skoff;
  const bf16* a1 = A + (size_t)ar1 * K + skoff;
  const bf16* b0 = BT + (size_t)(n0 + srow) * K + skoff;
  const bf16* b1 = BT + (size_t)(n0 + srow + 64) * K + skoff;

  const int fr = lane & 15;
  const int fq = lane >> 4;

  f32x4 acc[4][4];
#pragma unroll
  for (int m = 0; m < 4; ++m)
#pragma unroll
    for (int n = 0; n < 4; ++n) acc[m][n] = (f32x4){0.f, 0.f, 0.f, 0.f};

  const int nk = K >> 5;
  auto stage = [&](int buf, int kt) {
    gload_lds16(a0 + kt * 32, &sA[buf][wid * 16][0]);
    gload_lds16(a1 + kt * 32, &sA[buf][wid * 16 + 64][0]);
    gload_lds16(b0 + kt * 32, &sB[buf][wid * 16][0]);
    gload_lds16(b1 + kt * 32, &sB[buf][wid * 16 + 64][0]);
  };

  stage(0, 0);
  __syncthreads();
  const int wr = wid >> 1, wc = wid & 1;
  for (int kt = 0; kt < nk; ++kt) {
    const int cur = kt & 1;
    if (kt + 1 < nk) stage(cur ^ 1, kt + 1);
    bf16x8 af[4], bfr[4];
#pragma unroll
    for (int m = 0; m < 4; ++m)
      af[m] = *(const bf16x8*)&sA[cur][wr * 64 + m * 16 + fr][fq * 8];
#pragma unroll
    for (int n = 0; n < 4; ++n)
      bfr[n] = *(const bf16x8*)&sB[cur][wc * 64 + n * 16 + fr][fq * 8];
#pragma unroll
    for (int m = 0; m < 4; ++m)
#pragma unroll
      for (int n = 0; n < 4; ++n)
        acc[m][n] = __builtin_amdgcn_mfma_f32_16x16x32_bf16(af[m], bfr[n], acc[m][n], 0, 0, 0);
    __syncthreads();
  }

  float s = 1.f;
  if (SCALE) s = expf(*scale_ptr);
#pragma unroll
  for (int m = 0; m < 4; ++m) {
#pragma unroll
    for (int r = 0; r < 4; ++r) {
      const int p = m0 + wr * 64 + m * 16 + fq * 4 + r;
      if (p < cnt) {
        size_t crow;
        if (SCATTER_C) crow = perm[base + p];
        else if (SEG)  crow = base + p;
        else           crow = p;
#pragma unroll
        for (int n = 0; n < 4; ++n) {
          const int col = n0 + wc * 64 + n * 16 + fr;
          if (col < Nvalid) {
            float v = acc[m][n][r];
            if (RELU) v = fmaxf(v, 0.f);
            v *= s;
            if (C_BF16) ((bf16*)Cv)[crow * (size_t)ldc + col] = __float2bfloat16(v);
            else        ((float*)Cv)[crow * (size_t)ldc + col] = v;
          }
        }
      }
    }
  }
}

// ============ GEMM3: gemm3_occ — 128x192, BK=64, 4 waves, 80KB LDS -> 2 blocks/CU ============
// R6 A/B winner (~51 µs ≈ 930 TF vs 81 µs for the 256² counted-vmcnt template).
// Mechanism: 2 blocks/CU -> cross-block TLP hides the per-block barrier drain (m114);
// grid 128x8 = 1024 = exactly 2 packed rounds of 512 block-slots; mb-major XCD swizzle.
__global__ __launch_bounds__(256, 2) void gemm3_occ(
    const bf16* __restrict__ A, const bf16* __restrict__ BT,
    float* __restrict__ C, const float* __restrict__ scale_ptr) {
  extern __shared__ bf16 smem[];
  bf16* sA0 = smem;            // [2][128][64] = 32KB
  bf16* sB0 = smem + 16384;    // [2][192][64] = 48KB

  const int tid = threadIdx.x;
  const int lane = tid & 63, wid = tid >> 6;
  const int wr = wid >> 1, wc = wid & 1;     // 2x2; wave C = 64x96
  const int fr = lane & 15, fq = lane >> 4;

  const int bid = blockIdx.x;
  const int x = bid & 7, seq = bid >> 3;     // seq 0..127
  const int mb = x * 16 + (seq >> 3), nb = seq & 7;
  const int m0 = mb << 7, n0 = nb * 192;

  auto STAGE = [&](int t) {     // A 4 + B 6 loads/thread
    const int s = t & 1, koff = t << 6;
    bf16* da = sA0 + (s << 13);
#pragma unroll
    for (int L = 0; L < 4; ++L) {
      const int idx = (L << 8) + tid;
      const int r = idx >> 3, c = idx & 7;
      gload_lds16(A + (size_t)(m0 + r) * 1024 + koff + ((c ^ (r & 7)) << 3),
                  da + ((idx & ~63) << 3));
    }
    bf16* db = sB0 + s * 12288;
#pragma unroll
    for (int L = 0; L < 6; ++L) {
      const int idx = (L << 8) + tid;
      const int r = idx >> 3, c = idx & 7;
      gload_lds16(BT + (size_t)(n0 + r) * 1024 + koff + ((c ^ (r & 7)) << 3),
                  db + ((idx & ~63) << 3));
    }
  };
  auto LDA = [&](int s, int kk, bf16x8* dst) {
    const bf16* base = sA0 + (s << 13);
#pragma unroll
    for (int m = 0; m < 4; ++m) {
      const int row = (wr << 6) + (m << 4) + fr;
      dst[m] = *(const bf16x8*)(base + (row << 6) + ((((kk << 2) + fq) ^ (fr & 7)) << 3));
    }
  };
  auto LDB = [&](int s, int kk, bf16x8* dst) {
    const bf16* base = sB0 + s * 12288;
#pragma unroll
    for (int n = 0; n < 6; ++n) {
      const int row = wc * 96 + (n << 4) + fr;
      dst[n] = *(const bf16x8*)(base + (row << 6) + ((((kk << 2) + fq) ^ (fr & 7)) << 3));
    }
  };

  f32x4 acc[4][6];
#pragma unroll
  for (int m = 0; m < 4; ++m)
#pragma unroll
    for (int n = 0; n < 6; ++n) acc[m][n] = (f32x4){0.f, 0.f, 0.f, 0.f};

  STAGE(0);
  __syncthreads();
  const int nt = 16;
  for (int t = 0; t < nt; ++t) {
    const int s = t & 1;
    if (t + 1 < nt) STAGE(t + 1);
    bf16x8 a0[4], a1[4], b0[6], b1[6];
    LDA(s, 0, a0); LDB(s, 0, b0);
    LDA(s, 1, a1); LDB(s, 1, b1);
#pragma unroll
    for (int m = 0; m < 4; ++m)
#pragma unroll
      for (int n = 0; n < 6; ++n)
        acc[m][n] = __builtin_amdgcn_mfma_f32_16x16x32_bf16(a0[m], b0[n], acc[m][n], 0, 0, 0);
#pragma unroll
    for (int m = 0; m < 4; ++m)
#pragma unroll
      for (int n = 0; n < 6; ++n)
        acc[m][n] = __builtin_amdgcn_mfma_f32_16x16x32_bf16(a1[m], b1[n], acc[m][n], 0, 0, 0);
    __syncthreads();
  }

  const float sc = expf(*scale_ptr);
#pragma unroll
  for (int m = 0; m < 4; ++m) {
    const int grow = m0 + (wr << 6) + (m << 4) + (fq << 2);
#pragma unroll
    for (int r = 0; r < 4; ++r) {
#pragma unroll
      for (int n = 0; n < 6; ++n) {
        const int gcol = n0 + wc * 96 + (n << 4) + fr;
        if (gcol < 1380) C[(size_t)(grow + r) * 1380 + gcol] = acc[m][n][r] * sc;
      }
    }
  }
}

// ------- fused = normalize(0.2*a + 0.8*x), in place over F; vectorized loads -------
template <bool XB>
__global__ __launch_bounds__(256) void fuse_norm_k(const float* __restrict__ x,
                                                   const bf16* __restrict__ xb,
                                                   bf16* __restrict__ F) {
  const int row = blockIdx.x;
  const int t = threadIdx.x;
  const size_t roff = (size_t)row * 1024;
  us4 av = ((const us4*)(F + roff))[t];
  float xv[4];
  if (XB) {
    us4 xq = ((const us4*)(xb + roff))[t];
#pragma unroll
    for (int j = 0; j < 4; ++j) xv[j] = b2f(xq[j]);
  } else {
    float4 xf = ((const float4*)(x + roff))[t];
    xv[0] = xf.x; xv[1] = xf.y; xv[2] = xf.z; xv[3] = xf.w;
  }
  float f[4];
  float ss = 0.f;
#pragma unroll
  for (int j = 0; j < 4; ++j) {
    f[j] = 0.2f * b2f(av[j]) + 0.8f * xv[j];
    ss += f[j] * f[j];
  }
#pragma unroll
  for (int o = 32; o > 0; o >>= 1) ss += __shfl_down(ss, o);
  __shared__ float sred[4];
  if ((t & 63) == 0) sred[t >> 6] = ss;
  __syncthreads();
  const float rinv = 1.0f / sqrtf(sred[0] + sred[1] + sred[2] + sred[3]);
  us4 ov;
#pragma unroll
  for (int j = 0; j < 4; ++j) ov[j] = f2b(f[j] * rinv);
  ((us4*)(F + roff))[t] = ov;
}

extern "C" void kernel_launch(void* const* d_in, const int* in_sizes, int n_in,
                              void* d_out, int out_size, void* d_ws, size_t ws_size,
                              hipStream_t stream) {
  (void)in_sizes; (void)n_in; (void)out_size;
  const float* x    = (const float*)d_in[0];
  const int*   lab  = (const int*)d_in[1];
  const float* W1   = (const float*)d_in[2];
  const float* W2   = (const float*)d_in[3];
  const float* text = (const float*)d_in[4];
  const float* lsc  = (const float*)d_in[5];
  float* out = (float*)d_out;

  const int B = 16384, D = 1024, R = 256, NTP = 1536;

  char* p = (char*)d_ws;
  auto carve = [&](size_t bytes) {
    char* r = p;
    p += (bytes + 255) & ~(size_t)255;
    return r;
  };
  int*  meta  = (int*)carve(64);
  int*  bhist = (int*)carve(64 * 3 * 4);
  int*  boff  = (int*)carve(64 * 3 * 4);
  int*  perm  = (int*)carve((size_t)B * 4);
  bf16* Xb    = (bf16*)carve((size_t)B * D * 2);
  bf16* W1T   = (bf16*)carve((size_t)3 * R * D * 2);
  bf16* W2T   = (bf16*)carve((size_t)3 * D * R * 2);
  bf16* Tb    = (bf16*)carve((size_t)NTP * D * 2);
  bf16* H     = (bf16*)carve((size_t)B * R * 2);
  bf16* Fb    = (bf16*)carve((size_t)B * D * 2);
  const bool bigws = (size_t)(p - (char*)d_ws) <= ws_size;
  if (!bigws) Fb = Xb;

  hist_k<<<B / 256, 256, 0, stream>>>(lab, bhist);
  scan_k<<<1, 256, 0, stream>>>(bhist, boff, meta);
  scatter2_k<<<B / 256, 256, 0, stream>>>(lab, boff, perm);

  cvt_bf16_k<<<(B * D / 4 + 255) / 256, 256, 0, stream>>>(x, Xb, B * D / 4);
  {
    const int total = 3 * R * D + 3 * D * R + NTP * D;
    cvt_wt_k<<<(total + 255) / 256, 256, 0, stream>>>(W1, W2, text, W1T, W2T, Tb);
  }

  // GEMM1: H = relu(Xb[perm] @ W1T[dom]^T)   M=cnt N=256 K=1024
  dim3 g1(128, 2, 3);
  gemm_bt<true, true, false, true, true, false><<<g1, 256, 0, stream>>>(
      Xb, W1T, H, perm, meta, B, R, D, R, R, nullptr);
  // GEMM2: Fb[orig] = relu(H @ W2T[dom]^T)   M=cnt N=1024 K=256 (scatter)
  dim3 g2(128, 8, 3);
  gemm_bt<true, false, true, true, true, false><<<g2, 256, 0, stream>>>(
      H, W2T, Fb, perm, meta, B, D, R, D, D, nullptr);
  if (bigws) fuse_norm_k<true><<<B, 256, 0, stream>>>(x, Xb, Fb);
  else       fuse_norm_k<false><<<B, 256, 0, stream>>>(x, nullptr, Fb);

  // GEMM3: out = exp(ls) * Fb @ Tb^T   M=16384 N=1536(valid 1380) K=1024
  gemm3_occ<<<1024, 256, 81920, stream>>>(Fb, Tb, out, lsc);
}

// Round 8
// 169.584 us; speedup vs baseline: 1.4266x; 1.0039x over previous
//
#include <hip/hip_runtime.h>
#include <hip/hip_bf16.h>
#include <math.h>

using bf16 = __hip_bfloat16;
typedef __attribute__((ext_vector_type(8))) short bf16x8;
typedef __attribute__((ext_vector_type(4))) float f32x4;
typedef __attribute__((ext_vector_type(4))) unsigned short us4;

#define GAS __attribute__((address_space(1)))
#define LAS __attribute__((address_space(3)))

__device__ __forceinline__ void gload_lds16(const bf16* g, bf16* lds) {
  __builtin_amdgcn_global_load_lds((const GAS void*)g, (LAS void*)lds, 16, 0, 0);
}
__device__ __forceinline__ float b2f(unsigned short u) {
  union { unsigned short s; bf16 b; } x; x.s = u; return __bfloat162float(x.b);
}
__device__ __forceinline__ unsigned short f2b(float f) {
  union { unsigned short s; bf16 b; } x; x.b = __float2bfloat16(f); return x.s;
}

// ---------------- compaction (atomic-free, stable => deterministic) ----------------
__global__ __launch_bounds__(256) void hist_k(const int* __restrict__ lab,
                                              int* __restrict__ blockHist) {
  const int blk = blockIdx.x, t = threadIdx.x;
  const int lane = t & 63, w = t >> 6;
  const int d = lab[blk * 256 + t];
  __shared__ int wc[4][3];
#pragma unroll
  for (int dd = 0; dd < 3; ++dd) {
    unsigned long long m = __ballot(d == dd);
    if (lane == 0) wc[w][dd] = __popcll(m);
  }
  __syncthreads();
  if (t < 3) blockHist[blk * 3 + t] = wc[0][t] + wc[1][t] + wc[2][t] + wc[3][t];
}

__global__ __launch_bounds__(256) void scan_k(const int* __restrict__ blockHist,
                                              int* __restrict__ blockOff,
                                              int* __restrict__ meta) {
  __shared__ int h[64][3];
  __shared__ int tot[3];
  const int t = threadIdx.x;
  if (t < 192) h[t / 3][t % 3] = blockHist[t];
  __syncthreads();
  if (t < 3) {
    int s = 0;
    for (int b = 0; b < 64; ++b) { int v = h[b][t]; h[b][t] = s; s += v; }
    tot[t] = s;
    meta[t] = s;
  }
  __syncthreads();
  if (t == 0) { meta[4] = 0; meta[5] = tot[0]; meta[6] = tot[0] + tot[1]; }
  if (t < 192) {
    int b = t / 3, d = t % 3;
    int base = (d == 0) ? 0 : (d == 1 ? tot[0] : tot[0] + tot[1]);
    blockOff[t] = base + h[b][d];
  }
}

__global__ __launch_bounds__(256) void scatter2_k(const int* __restrict__ lab,
                                                  const int* __restrict__ blockOff,
                                                  int* __restrict__ perm) {
  const int blk = blockIdx.x, t = threadIdx.x;
  const int lane = t & 63, w = t >> 6;
  const int i = blk * 256 + t;
  const int d = lab[i];
  __shared__ int wc[4][3];
  unsigned long long mymask = 0;
#pragma unroll
  for (int dd = 0; dd < 3; ++dd) {
    unsigned long long m = __ballot(d == dd);
    if (lane == 0) wc[w][dd] = __popcll(m);
    if (dd == d) mymask = m;
  }
  __syncthreads();
  int woff = 0;
  for (int ww = 0; ww < w; ++ww) woff += wc[ww][d];
  const unsigned long long lt = ((unsigned long long)1 << lane) - 1;
  const int rank = blockOff[blk * 3 + d] + woff + __popcll(mymask & lt);
  perm[rank] = i;
}

// ------------- merged conversions: x (vec4) | W1^T | W2^T | text (pad 1536) -------------
__global__ __launch_bounds__(256) void cvt_all_k(const float* __restrict__ x,
                                                 const float* __restrict__ W1,
                                                 const float* __restrict__ W2,
                                                 const float* __restrict__ txt,
                                                 bf16* __restrict__ Xb,
                                                 bf16* __restrict__ W1T,
                                                 bf16* __restrict__ W2T,
                                                 bf16* __restrict__ Tb) {
  int i = blockIdx.x * 256 + threadIdx.x;
  const int nx = 16384 * 1024 / 4;       // x, float4 path
  if (i < nx) {
    float4 v = ((const float4*)x)[i];
    bf16 t[4] = {__float2bfloat16(v.x), __float2bfloat16(v.y),
                 __float2bfloat16(v.z), __float2bfloat16(v.w)};
    ((us4*)Xb)[i] = *(const us4*)t;
    return;
  }
  int j = i - nx;
  const int n1 = 3 * 256 * 1024;
  const int n2 = n1 + 3 * 1024 * 256;
  const int n3 = n2 + 1536 * 1024;
  if (j < n1) {
    int d = j >> 18, rem = j & 262143;
    int r = rem >> 10, k = rem & 1023;
    W1T[j] = __float2bfloat16(W1[(size_t)d * 262144 + (size_t)k * 256 + r]);
  } else if (j < n2) {
    int jj = j - n1;
    int d = jj >> 18, rem = jj & 262143;
    int n = rem >> 8, k = rem & 255;
    W2T[jj] = __float2bfloat16(W2[(size_t)d * 262144 + (size_t)k * 1024 + n]);
  } else if (j < n3) {
    int jj = j - n2;
    Tb[jj] = (jj < 1380 * 1024) ? __float2bfloat16(txt[jj]) : __float2bfloat16(0.f);
  }
}

// ---------------- 128^2 2-phase GEMM for GEMM1/GEMM2, chunk-XOR LDS swizzle ----------------
// BK=32 -> 4 chunks of 8 bf16; both-sides XOR with (row&3): linear LDS dest, pre-swizzled
// global source (rule 21), matching XOR on ds_read. Residual 4-way conflict (was 8-way).
// EPI=0: C=relu(acc)->bf16 at compacted row (GEMM1).
// EPI=1: g=0.2*relu(acc)+0.8*x[crow], scatter bf16 to Fb[crow], per-row ss partial ->
//        ssp[blockIdx.y][crow] (non-atomic, each slot one writer => deterministic).
template <bool SEG, bool GATHER_A, int EPI>
__global__ __launch_bounds__(256) void gemm_bt(
    const bf16* __restrict__ A, const bf16* __restrict__ BT, bf16* __restrict__ Cv,
    const int* __restrict__ perm, const int* __restrict__ meta, int Mfull, int N,
    int K, int ldc, int Nvalid,
    const float* __restrict__ xf, float* __restrict__ ssp) {
  int cnt = Mfull, base = 0;
  if (SEG) {
    int dom = blockIdx.z;
    cnt = meta[dom];
    base = meta[4 + dom];
    BT += (size_t)dom * N * K;
  }
  const int m0 = blockIdx.x * 128;
  if (m0 >= cnt) return;
  const int n0 = blockIdx.y * 128;

  __shared__ bf16 sA[2][128][32];
  __shared__ bf16 sB[2][128][32];

  const int tid = threadIdx.x;
  const int wid = tid >> 6;
  const int lane = tid & 63;

  const int srow = (wid << 4) + (lane >> 2);
  // pre-swizzled source chunk: lane writes LDS slot (srow, lane&3); feed it global
  // chunk (lane&3) ^ (srow&3); srow&3 == (lane>>2)&3
  const int skoff = (((lane & 3) ^ ((lane >> 2) & 3)) << 3);

  int p0 = m0 + srow;       if (p0 > cnt - 1) p0 = cnt - 1;
  int p1 = m0 + srow + 64;  if (p1 > cnt - 1) p1 = cnt - 1;
  long ar0, ar1;
  if (GATHER_A) { ar0 = perm[base + p0]; ar1 = perm[base + p1]; }
  else          { ar0 = base + p0;       ar1 = base + p1; }
  const bf16* a0 = A + (size_t)ar0 * K + skoff;
  const bf16* a1 = A + (size_t)ar1 * K + skoff;
  const bf16* b0 = BT + (size_t)(n0 + srow) * K + skoff;
  const bf16* b1 = BT + (size_t)(n0 + srow + 64) * K + skoff;

  const int fr = lane & 15;
  const int fq = lane >> 4;
  const int rchunk = (fq ^ (fr & 3)) << 3;   // read-side XOR (row&3 == fr&3)

  f32x4 acc[4][4];
#pragma unroll
  for (int m = 0; m < 4; ++m)
#pragma unroll
    for (int n = 0; n < 4; ++n) acc[m][n] = (f32x4){0.f, 0.f, 0.f, 0.f};

  const int nk = K >> 5;
  auto stage = [&](int buf, int kt) {
    gload_lds16(a0 + kt * 32, &sA[buf][wid * 16][0]);
    gload_lds16(a1 + kt * 32, &sA[buf][wid * 16 + 64][0]);
    gload_lds16(b0 + kt * 32, &sB[buf][wid * 16][0]);
    gload_lds16(b1 + kt * 32, &sB[buf][wid * 16 + 64][0]);
  };

  stage(0, 0);
  __syncthreads();
  const int wr = wid >> 1, wc = wid & 1;
  for (int kt = 0; kt < nk; ++kt) {
    const int cur = kt & 1;
    if (kt + 1 < nk) stage(cur ^ 1, kt + 1);
    bf16x8 af[4], bfr[4];
#pragma unroll
    for (int m = 0; m < 4; ++m)
      af[m] = *(const bf16x8*)&sA[cur][wr * 64 + m * 16 + fr][rchunk];
#pragma unroll
    for (int n = 0; n < 4; ++n)
      bfr[n] = *(const bf16x8*)&sB[cur][wc * 64 + n * 16 + fr][rchunk];
#pragma unroll
    for (int m = 0; m < 4; ++m)
#pragma unroll
      for (int n = 0; n < 4; ++n)
        acc[m][n] = __builtin_amdgcn_mfma_f32_16x16x32_bf16(af[m], bfr[n], acc[m][n], 0, 0, 0);
    __syncthreads();
  }

  if (EPI == 0) {
#pragma unroll
    for (int m = 0; m < 4; ++m) {
#pragma unroll
      for (int r = 0; r < 4; ++r) {
        const int p = m0 + wr * 64 + m * 16 + fq * 4 + r;
        if (p < cnt) {
          const size_t crow = SEG ? (size_t)(base + p) : (size_t)p;
#pragma unroll
          for (int n = 0; n < 4; ++n) {
            const int col = n0 + wc * 64 + n * 16 + fr;
            if (col < Nvalid)
              Cv[crow * (size_t)ldc + col] = __float2bfloat16(fmaxf(acc[m][n][r], 0.f));
          }
        }
      }
    }
  } else {
    __shared__ float ssred[128][2];
#pragma unroll
    for (int m = 0; m < 4; ++m) {
#pragma unroll
      for (int r = 0; r < 4; ++r) {
        const int lr = wr * 64 + m * 16 + fq * 4 + r;
        const int p = m0 + lr;
        float rowss = 0.f;
        if (p < cnt) {
          const size_t crow = (size_t)perm[base + p];
#pragma unroll
          for (int n = 0; n < 4; ++n) {
            const int col = n0 + wc * 64 + n * 16 + fr;
            const float g = 0.2f * fmaxf(acc[m][n][r], 0.f) + 0.8f * xf[crow * 1024 + col];
            Cv[crow * (size_t)ldc + col] = __float2bfloat16(g);
            rowss += g * g;
          }
        }
        rowss += __shfl_xor(rowss, 1, 16);
        rowss += __shfl_xor(rowss, 2, 16);
        rowss += __shfl_xor(rowss, 4, 16);
        rowss += __shfl_xor(rowss, 8, 16);
        if (fr == 0) ssred[lr][wc] = rowss;
      }
    }
    __syncthreads();
    if (tid < 128) {
      const int p = m0 + tid;
      if (p < cnt) {
        const int crow = perm[base + p];
        ssp[(size_t)blockIdx.y * 16384 + crow] = ssred[tid][0] + ssred[tid][1];
      }
    }
  }
}

// --------- rinv[row] = 1/sqrt(sum_nb ssp[nb][row]) — deterministic reduce ---------
__global__ __launch_bounds__(256) void rinv_k(const float* __restrict__ ssp,
                                              float* __restrict__ rinv) {
  const int r = blockIdx.x * 256 + threadIdx.x;
  float s = 0.f;
#pragma unroll
  for (int b = 0; b < 8; ++b) s += ssp[b * 16384 + r];
  rinv[r] = rsqrtf(s);
}

// ============ GEMM3: 128x192, BK=64, 4 waves, 80KB LDS -> 2 blocks/CU (R6 winner) ============
// out[row][col] = exp(ls) * rinv[row] * (g[row] . t[col]) — normalization folded into epilogue.
__global__ __launch_bounds__(256, 2) void gemm3_occ(
    const bf16* __restrict__ A, const bf16* __restrict__ BT,
    float* __restrict__ C, const float* __restrict__ scale_ptr,
    const float* __restrict__ rinv) {
  extern __shared__ bf16 smem[];
  bf16* sA0 = smem;            // [2][128][64] = 32KB
  bf16* sB0 = smem + 16384;    // [2][192][64] = 48KB

  const int tid = threadIdx.x;
  const int lane = tid & 63, wid = tid >> 6;
  const int wr = wid >> 1, wc = wid & 1;     // 2x2; wave C = 64x96
  const int fr = lane & 15, fq = lane >> 4;

  const int bid = blockIdx.x;
  const int x = bid & 7, seq = bid >> 3;     // seq 0..127
  const int mb = x * 16 + (seq >> 3), nb = seq & 7;
  const int m0 = mb << 7, n0 = nb * 192;

  auto STAGE = [&](int t) {     // A 4 + B 6 loads/thread
    const int s = t & 1, koff = t << 6;
    bf16* da = sA0 + (s << 13);
#pragma unroll
    for (int L = 0; L < 4; ++L) {
      const int idx = (L << 8) + tid;
      const int r = idx >> 3, c = idx & 7;
      gload_lds16(A + (size_t)(m0 + r) * 1024 + koff + ((c ^ (r & 7)) << 3),
                  da + ((idx & ~63) << 3));
    }
    bf16* db = sB0 + s * 12288;
#pragma unroll
    for (int L = 0; L < 6; ++L) {
      const int idx = (L << 8) + tid;
      const int r = idx >> 3, c = idx & 7;
      gload_lds16(BT + (size_t)(n0 + r) * 1024 + koff + ((c ^ (r & 7)) << 3),
                  db + ((idx & ~63) << 3));
    }
  };
  auto LDA = [&](int s, int kk, bf16x8* dst) {
    const bf16* base = sA0 + (s << 13);
#pragma unroll
    for (int m = 0; m < 4; ++m) {
      const int row = (wr << 6) + (m << 4) + fr;
      dst[m] = *(const bf16x8*)(base + (row << 6) + ((((kk << 2) + fq) ^ (fr & 7)) << 3));
    }
  };
  auto LDB = [&](int s, int kk, bf16x8* dst) {
    const bf16* base = sB0 + s * 12288;
#pragma unroll
    for (int n = 0; n < 6; ++n) {
      const int row = wc * 96 + (n << 4) + fr;
      dst[n] = *(const bf16x8*)(base + (row << 6) + ((((kk << 2) + fq) ^ (fr & 7)) << 3));
    }
  };

  f32x4 acc[4][6];
#pragma unroll
  for (int m = 0; m < 4; ++m)
#pragma unroll
    for (int n = 0; n < 6; ++n) acc[m][n] = (f32x4){0.f, 0.f, 0.f, 0.f};

  STAGE(0);
  __syncthreads();
  const int nt = 16;
  for (int t = 0; t < nt; ++t) {
    const int s = t & 1;
    if (t + 1 < nt) STAGE(t + 1);
    bf16x8 a0[4], a1[4], b0[6], b1[6];
    LDA(s, 0, a0); LDB(s, 0, b0);
    LDA(s, 1, a1); LDB(s, 1, b1);
#pragma unroll
    for (int m = 0; m < 4; ++m)
#pragma unroll
      for (int n = 0; n < 6; ++n)
        acc[m][n] = __builtin_amdgcn_mfma_f32_16x16x32_bf16(a0[m], b0[n], acc[m][n], 0, 0, 0);
#pragma unroll
    for (int m = 0; m < 4; ++m)
#pragma unroll
      for (int n = 0; n < 6; ++n)
        acc[m][n] = __builtin_amdgcn_mfma_f32_16x16x32_bf16(a1[m], b1[n], acc[m][n], 0, 0, 0);
    __syncthreads();
  }

  const float sc = expf(*scale_ptr);
#pragma unroll
  for (int m = 0; m < 4; ++m) {
    const int grow = m0 + (wr << 6) + (m << 4) + (fq << 2);
#pragma unroll
    for (int r = 0; r < 4; ++r) {
      const float rv = sc * rinv[grow + r];
#pragma unroll
      for (int n = 0; n < 6; ++n) {
        const int gcol = n0 + wc * 96 + (n << 4) + fr;
        if (gcol < 1380) C[(size_t)(grow + r) * 1380 + gcol] = acc[m][n][r] * rv;
      }
    }
  }
}

extern "C" void kernel_launch(void* const* d_in, const int* in_sizes, int n_in,
                              void* d_out, int out_size, void* d_ws, size_t ws_size,
                              hipStream_t stream) {
  (void)in_sizes; (void)n_in; (void)out_size; (void)ws_size;
  const float* x    = (const float*)d_in[0];
  const int*   lab  = (const int*)d_in[1];
  const float* W1   = (const float*)d_in[2];
  const float* W2   = (const float*)d_in[3];
  const float* text = (const float*)d_in[4];
  const float* lsc  = (const float*)d_in[5];
  float* out = (float*)d_out;

  const int B = 16384, D = 1024, R = 256, NTP = 1536;

  char* p = (char*)d_ws;
  auto carve = [&](size_t bytes) {
    char* r = p;
    p += (bytes + 255) & ~(size_t)255;
    return r;
  };
  int*   meta  = (int*)carve(64);
  int*   bhist = (int*)carve(64 * 3 * 4);
  int*   boff  = (int*)carve(64 * 3 * 4);
  int*   perm  = (int*)carve((size_t)B * 4);
  float* ssp   = (float*)carve((size_t)8 * B * 4);
  float* rinv  = (float*)carve((size_t)B * 4);
  bf16*  Xb    = (bf16*)carve((size_t)B * D * 2);
  bf16*  W1T   = (bf16*)carve((size_t)3 * R * D * 2);
  bf16*  W2T   = (bf16*)carve((size_t)3 * D * R * 2);
  bf16*  Tb    = (bf16*)carve((size_t)NTP * D * 2);
  bf16*  H     = (bf16*)carve((size_t)B * R * 2);
  bf16*  Fb    = (bf16*)carve((size_t)B * D * 2);

  hist_k<<<B / 256, 256, 0, stream>>>(lab, bhist);
  scan_k<<<1, 256, 0, stream>>>(bhist, boff, meta);
  scatter2_k<<<B / 256, 256, 0, stream>>>(lab, boff, perm);

  {
    const int nx = B * D / 4;
    const int total = nx + 3 * R * D + 3 * D * R + NTP * D;
    cvt_all_k<<<(total + 255) / 256, 256, 0, stream>>>(x, W1, W2, text, Xb, W1T, W2T, Tb);
  }

  // GEMM1: H = relu(Xb[perm] @ W1T[dom]^T)   M=cnt N=256 K=1024 (compacted out)
  dim3 g1(128, 2, 3);
  gemm_bt<true, true, 0><<<g1, 256, 0, stream>>>(
      Xb, W1T, H, perm, meta, B, R, D, R, R, nullptr, nullptr);
  // GEMM2: Fb[crow] = 0.2*relu(H @ W2T[dom]^T) + 0.8*x  + ssp partials (scatter)
  dim3 g2(128, 8, 3);
  gemm_bt<true, false, 1><<<g2, 256, 0, stream>>>(
      H, W2T, Fb, perm, meta, B, D, R, D, D, x, ssp);
  // rinv[row] = 1/||fused_row||
  rinv_k<<<B / 256, 256, 0, stream>>>(ssp, rinv);
  // GEMM3: out = exp(ls) * rinv[row] * (Fb @ Tb^T)
  gemm3_occ<<<1024, 256, 81920, stream>>>(Fb, Tb, out, lsc, rinv);
}

// Round 9
// 162.375 us; speedup vs baseline: 1.4899x; 1.0444x over previous
//
#include <hip/hip_runtime.h>
#include <hip/hip_bf16.h>
#include <math.h>

using bf16 = __hip_bfloat16;
typedef __attribute__((ext_vector_type(8))) short bf16x8;
typedef __attribute__((ext_vector_type(4))) float f32x4;
typedef __attribute__((ext_vector_type(4))) unsigned short us4;

#define GAS __attribute__((address_space(1)))
#define LAS __attribute__((address_space(3)))

__device__ __forceinline__ void gload_lds16(const bf16* g, bf16* lds) {
  __builtin_amdgcn_global_load_lds((const GAS void*)g, (LAS void*)lds, 16, 0, 0);
}
__device__ __forceinline__ float b2f(unsigned short u) {
  union { unsigned short s; bf16 b; } x; x.s = u; return __bfloat162float(x.b);
}

// ---------------- compaction (atomic-free, stable => deterministic) ----------------
__global__ __launch_bounds__(256) void hist_k(const int* __restrict__ lab,
                                              int* __restrict__ blockHist) {
  const int blk = blockIdx.x, t = threadIdx.x;
  const int lane = t & 63, w = t >> 6;
  const int d = lab[blk * 256 + t];
  __shared__ int wc[4][3];
#pragma unroll
  for (int dd = 0; dd < 3; ++dd) {
    unsigned long long m = __ballot(d == dd);
    if (lane == 0) wc[w][dd] = __popcll(m);
  }
  __syncthreads();
  if (t < 3) blockHist[blk * 3 + t] = wc[0][t] + wc[1][t] + wc[2][t] + wc[3][t];
}

__global__ __launch_bounds__(256) void scan_k(const int* __restrict__ blockHist,
                                              int* __restrict__ blockOff,
                                              int* __restrict__ meta) {
  __shared__ int h[64][3];
  __shared__ int tot[3];
  const int t = threadIdx.x;
  if (t < 192) h[t / 3][t % 3] = blockHist[t];
  __syncthreads();
  if (t < 3) {
    int s = 0;
    for (int b = 0; b < 64; ++b) { int v = h[b][t]; h[b][t] = s; s += v; }
    tot[t] = s;
    meta[t] = s;
  }
  __syncthreads();
  if (t == 0) { meta[4] = 0; meta[5] = tot[0]; meta[6] = tot[0] + tot[1]; }
  if (t < 192) {
    int b = t / 3, d = t % 3;
    int base = (d == 0) ? 0 : (d == 1 ? tot[0] : tot[0] + tot[1]);
    blockOff[t] = base + h[b][d];
  }
}

__global__ __launch_bounds__(256) void scatter2_k(const int* __restrict__ lab,
                                                  const int* __restrict__ blockOff,
                                                  int* __restrict__ perm) {
  const int blk = blockIdx.x, t = threadIdx.x;
  const int lane = t & 63, w = t >> 6;
  const int i = blk * 256 + t;
  const int d = lab[i];
  __shared__ int wc[4][3];
  unsigned long long mymask = 0;
#pragma unroll
  for (int dd = 0; dd < 3; ++dd) {
    unsigned long long m = __ballot(d == dd);
    if (lane == 0) wc[w][dd] = __popcll(m);
    if (dd == d) mymask = m;
  }
  __syncthreads();
  int woff = 0;
  for (int ww = 0; ww < w; ++ww) woff += wc[ww][d];
  const unsigned long long lt = ((unsigned long long)1 << lane) - 1;
  const int rank = blockOff[blk * 3 + d] + woff + __popcll(mymask & lt);
  perm[rank] = i;
}

// ------- merged conversions (grid-stride): x (vec4) | W1^T | W2^T | text (pad 1536) -------
__global__ __launch_bounds__(256) void cvt_all_k(const float* __restrict__ x,
                                                 const float* __restrict__ W1,
                                                 const float* __restrict__ W2,
                                                 const float* __restrict__ txt,
                                                 bf16* __restrict__ Xb,
                                                 bf16* __restrict__ W1T,
                                                 bf16* __restrict__ W2T,
                                                 bf16* __restrict__ Tb) {
  const int nx = 16384 * 1024 / 4;
  const int n1 = 3 * 256 * 1024;
  const int n2 = n1 + 3 * 1024 * 256;
  const int n3 = n2 + 1536 * 1024;
  const int total = nx + n3;
  for (int i = blockIdx.x * 256 + threadIdx.x; i < total; i += 4096 * 256) {
    if (i < nx) {
      float4 v = ((const float4*)x)[i];
      bf16 t[4] = {__float2bfloat16(v.x), __float2bfloat16(v.y),
                   __float2bfloat16(v.z), __float2bfloat16(v.w)};
      ((us4*)Xb)[i] = *(const us4*)t;
      continue;
    }
    int j = i - nx;
    if (j < n1) {
      int d = j >> 18, rem = j & 262143;
      int r = rem >> 10, k = rem & 1023;
      W1T[j] = __float2bfloat16(W1[(size_t)d * 262144 + (size_t)k * 256 + r]);
    } else if (j < n2) {
      int jj = j - n1;
      int d = jj >> 18, rem = jj & 262143;
      int n = rem >> 8, k = rem & 255;
      W2T[jj] = __float2bfloat16(W2[(size_t)d * 262144 + (size_t)k * 1024 + n]);
    } else {
      int jj = j - n2;
      Tb[jj] = (jj < 1380 * 1024) ? __float2bfloat16(txt[jj]) : __float2bfloat16(0.f);
    }
  }
}

// ---------------- 128^2 2-phase GEMM for GEMM1/GEMM2, chunk-XOR LDS swizzle ----------------
// Flat 1-D grid, XCD-interleaved decode: x=bid&7 (XCD), n = seq%NBLK, dm = x + 8*(seq/NBLK),
// d = dm>>7, m = dm&127. All NBLK n-panels of one (d,m) land on ONE XCD -> A/H panel L2-hits.
// dm stride-8 interleave keeps active dms (clustered at domain-segment starts) balanced.
// EPI=0: C=relu(acc)->bf16 at compacted row (GEMM1).
// EPI=1: g=0.2*relu(acc)+0.8*Xb[crow] (bf16 read), scatter bf16 to Fb[crow], per-row ss
//        partial -> ssp[n][crow] (one writer per slot => deterministic).
template <bool GATHER_A, int EPI, int NBLK>
__global__ __launch_bounds__(256) void gemm_bt(
    const bf16* __restrict__ A, const bf16* __restrict__ BT, bf16* __restrict__ Cv,
    const int* __restrict__ perm, const int* __restrict__ meta, int N,
    int K, int ldc, int Nvalid,
    const bf16* __restrict__ xb, float* __restrict__ ssp) {
  const int bid = blockIdx.x;
  const int xcd = bid & 7;
  const int seq = bid >> 3;
  const int nblkidx = seq % NBLK;
  const int dm = xcd + 8 * (seq / NBLK);
  const int dom = dm >> 7;
  const int mblk = dm & 127;

  const int cnt = meta[dom];
  const int base = meta[4 + dom];
  BT += (size_t)dom * N * K;

  const int m0 = mblk * 128;
  if (m0 >= cnt) return;
  const int n0 = nblkidx * 128;

  __shared__ bf16 sA[2][128][32];
  __shared__ bf16 sB[2][128][32];

  const int tid = threadIdx.x;
  const int wid = tid >> 6;
  const int lane = tid & 63;

  const int srow = (wid << 4) + (lane >> 2);
  const int skoff = (((lane & 3) ^ ((lane >> 2) & 3)) << 3);

  int p0 = m0 + srow;       if (p0 > cnt - 1) p0 = cnt - 1;
  int p1 = m0 + srow + 64;  if (p1 > cnt - 1) p1 = cnt - 1;
  long ar0, ar1;
  if (GATHER_A) { ar0 = perm[base + p0]; ar1 = perm[base + p1]; }
  else          { ar0 = base + p0;       ar1 = base + p1; }
  const bf16* a0 = A + (size_t)ar0 * K + skoff;
  const bf16* a1 = A + (size_t)ar1 * K + skoff;
  const bf16* b0 = BT + (size_t)(n0 + srow) * K + skoff;
  const bf16* b1 = BT + (size_t)(n0 + srow + 64) * K + skoff;

  const int fr = lane & 15;
  const int fq = lane >> 4;
  const int rchunk = (fq ^ (fr & 3)) << 3;

  f32x4 acc[4][4];
#pragma unroll
  for (int m = 0; m < 4; ++m)
#pragma unroll
    for (int n = 0; n < 4; ++n) acc[m][n] = (f32x4){0.f, 0.f, 0.f, 0.f};

  const int nk = K >> 5;
  auto stage = [&](int buf, int kt) {
    gload_lds16(a0 + kt * 32, &sA[buf][wid * 16][0]);
    gload_lds16(a1 + kt * 32, &sA[buf][wid * 16 + 64][0]);
    gload_lds16(b0 + kt * 32, &sB[buf][wid * 16][0]);
    gload_lds16(b1 + kt * 32, &sB[buf][wid * 16 + 64][0]);
  };

  stage(0, 0);
  __syncthreads();
  const int wr = wid >> 1, wc = wid & 1;
  for (int kt = 0; kt < nk; ++kt) {
    const int cur = kt & 1;
    if (kt + 1 < nk) stage(cur ^ 1, kt + 1);
    bf16x8 af[4], bfr[4];
#pragma unroll
    for (int m = 0; m < 4; ++m)
      af[m] = *(const bf16x8*)&sA[cur][wr * 64 + m * 16 + fr][rchunk];
#pragma unroll
    for (int n = 0; n < 4; ++n)
      bfr[n] = *(const bf16x8*)&sB[cur][wc * 64 + n * 16 + fr][rchunk];
#pragma unroll
    for (int m = 0; m < 4; ++m)
#pragma unroll
      for (int n = 0; n < 4; ++n)
        acc[m][n] = __builtin_amdgcn_mfma_f32_16x16x32_bf16(af[m], bfr[n], acc[m][n], 0, 0, 0);
    __syncthreads();
  }

  if (EPI == 0) {
#pragma unroll
    for (int m = 0; m < 4; ++m) {
#pragma unroll
      for (int r = 0; r < 4; ++r) {
        const int p = m0 + wr * 64 + m * 16 + fq * 4 + r;
        if (p < cnt) {
          const size_t crow = (size_t)(base + p);
#pragma unroll
          for (int n = 0; n < 4; ++n) {
            const int col = n0 + wc * 64 + n * 16 + fr;
            if (col < Nvalid)
              Cv[crow * (size_t)ldc + col] = __float2bfloat16(fmaxf(acc[m][n][r], 0.f));
          }
        }
      }
    }
  } else {
    __shared__ float ssred[128][2];
#pragma unroll
    for (int m = 0; m < 4; ++m) {
#pragma unroll
      for (int r = 0; r < 4; ++r) {
        const int lr = wr * 64 + m * 16 + fq * 4 + r;
        const int p = m0 + lr;
        float rowss = 0.f;
        if (p < cnt) {
          const size_t crow = (size_t)perm[base + p];
#pragma unroll
          for (int n = 0; n < 4; ++n) {
            const int col = n0 + wc * 64 + n * 16 + fr;
            const float g = 0.2f * fmaxf(acc[m][n][r], 0.f) +
                            0.8f * b2f(*(const unsigned short*)&xb[crow * 1024 + col]);
            Cv[crow * (size_t)ldc + col] = __float2bfloat16(g);
            rowss += g * g;
          }
        }
        rowss += __shfl_xor(rowss, 1, 16);
        rowss += __shfl_xor(rowss, 2, 16);
        rowss += __shfl_xor(rowss, 4, 16);
        rowss += __shfl_xor(rowss, 8, 16);
        if (fr == 0) ssred[lr][wc] = rowss;
      }
    }
    __syncthreads();
    if (tid < 128) {
      const int p = m0 + tid;
      if (p < cnt) {
        const int crow = perm[base + p];
        ssp[(size_t)nblkidx * 16384 + crow] = ssred[tid][0] + ssred[tid][1];
      }
    }
  }
}

// ============ GEMM3: 128x192, BK=64, 4 waves, 80KB LDS -> 2 blocks/CU (R6 winner) ============
// out[row][col] = exp(ls) * rinv[row] * (g[row].t[col]); rinv computed in-kernel from ssp.
__global__ __launch_bounds__(256, 2) void gemm3_occ(
    const bf16* __restrict__ A, const bf16* __restrict__ BT,
    float* __restrict__ C, const float* __restrict__ scale_ptr,
    const float* __restrict__ ssp) {
  extern __shared__ bf16 smem[];
  bf16* sA0 = smem;            // [2][128][64] = 32KB
  bf16* sB0 = smem + 16384;    // [2][192][64] = 48KB

  const int tid = threadIdx.x;
  const int lane = tid & 63, wid = tid >> 6;
  const int wr = wid >> 1, wc = wid & 1;     // 2x2; wave C = 64x96
  const int fr = lane & 15, fq = lane >> 4;

  const int bid = blockIdx.x;
  const int x = bid & 7, seq = bid >> 3;     // seq 0..127
  const int mb = x * 16 + (seq >> 3), nb = seq & 7;
  const int m0 = mb << 7, n0 = nb * 192;

  auto STAGE = [&](int t) {     // A 4 + B 6 loads/thread
    const int s = t & 1, koff = t << 6;
    bf16* da = sA0 + (s << 13);
#pragma unroll
    for (int L = 0; L < 4; ++L) {
      const int idx = (L << 8) + tid;
      const int r = idx >> 3, c = idx & 7;
      gload_lds16(A + (size_t)(m0 + r) * 1024 + koff + ((c ^ (r & 7)) << 3),
                  da + ((idx & ~63) << 3));
    }
    bf16* db = sB0 + s * 12288;
#pragma unroll
    for (int L = 0; L < 6; ++L) {
      const int idx = (L << 8) + tid;
      const int r = idx >> 3, c = idx & 7;
      gload_lds16(BT + (size_t)(n0 + r) * 1024 + koff + ((c ^ (r & 7)) << 3),
                  db + ((idx & ~63) << 3));
    }
  };
  auto LDA = [&](int s, int kk, bf16x8* dst) {
    const bf16* base = sA0 + (s << 13);
#pragma unroll
    for (int m = 0; m < 4; ++m) {
      const int row = (wr << 6) + (m << 4) + fr;
      dst[m] = *(const bf16x8*)(base + (row << 6) + ((((kk << 2) + fq) ^ (fr & 7)) << 3));
    }
  };
  auto LDB = [&](int s, int kk, bf16x8* dst) {
    const bf16* base = sB0 + s * 12288;
#pragma unroll
    for (int n = 0; n < 6; ++n) {
      const int row = wc * 96 + (n << 4) + fr;
      dst[n] = *(const bf16x8*)(base + (row << 6) + ((((kk << 2) + fq) ^ (fr & 7)) << 3));
    }
  };

  f32x4 acc[4][6];
#pragma unroll
  for (int m = 0; m < 4; ++m)
#pragma unroll
    for (int n = 0; n < 6; ++n) acc[m][n] = (f32x4){0.f, 0.f, 0.f, 0.f};

  STAGE(0);
  __syncthreads();
  const int nt = 16;
  for (int t = 0; t < nt; ++t) {
    const int s = t & 1;
    if (t + 1 < nt) STAGE(t + 1);
    bf16x8 a0[4], a1[4], b0[6], b1[6];
    LDA(s, 0, a0); LDB(s, 0, b0);
    LDA(s, 1, a1); LDB(s, 1, b1);
#pragma unroll
    for (int m = 0; m < 4; ++m)
#pragma unroll
      for (int n = 0; n < 6; ++n)
        acc[m][n] = __builtin_amdgcn_mfma_f32_16x16x32_bf16(a0[m], b0[n], acc[m][n], 0, 0, 0);
#pragma unroll
    for (int m = 0; m < 4; ++m)
#pragma unroll
      for (int n = 0; n < 6; ++n)
        acc[m][n] = __builtin_amdgcn_mfma_f32_16x16x32_bf16(a1[m], b1[n], acc[m][n], 0, 0, 0);
    __syncthreads();
  }

  // in-kernel rinv for this block's 128 rows (replaces rinv_k launch)
  float* rlds = (float*)smem;
  if (tid < 128) {
    float s = 0.f;
#pragma unroll
    for (int b = 0; b < 8; ++b) s += ssp[b * 16384 + m0 + tid];
    rlds[tid] = rsqrtf(s);
  }
  __syncthreads();

  const float sc = expf(*scale_ptr);
#pragma unroll
  for (int m = 0; m < 4; ++m) {
    const int lrow = (wr << 6) + (m << 4) + (fq << 2);
    const int grow = m0 + lrow;
#pragma unroll
    for (int r = 0; r < 4; ++r) {
      const float rv = sc * rlds[lrow + r];
#pragma unroll
      for (int n = 0; n < 6; ++n) {
        const int gcol = n0 + wc * 96 + (n << 4) + fr;
        if (gcol < 1380) C[(size_t)(grow + r) * 1380 + gcol] = acc[m][n][r] * rv;
      }
    }
  }
}

extern "C" void kernel_launch(void* const* d_in, const int* in_sizes, int n_in,
                              void* d_out, int out_size, void* d_ws, size_t ws_size,
                              hipStream_t stream) {
  (void)in_sizes; (void)n_in; (void)out_size; (void)ws_size;
  const float* x    = (const float*)d_in[0];
  const int*   lab  = (const int*)d_in[1];
  const float* W1   = (const float*)d_in[2];
  const float* W2   = (const float*)d_in[3];
  const float* text = (const float*)d_in[4];
  const float* lsc  = (const float*)d_in[5];
  float* out = (float*)d_out;

  const int B = 16384, D = 1024, R = 256, NTP = 1536;

  char* p = (char*)d_ws;
  auto carve = [&](size_t bytes) {
    char* r = p;
    p += (bytes + 255) & ~(size_t)255;
    return r;
  };
  int*   meta  = (int*)carve(64);
  int*   bhist = (int*)carve(64 * 3 * 4);
  int*   boff  = (int*)carve(64 * 3 * 4);
  int*   perm  = (int*)carve((size_t)B * 4);
  float* ssp   = (float*)carve((size_t)8 * B * 4);
  bf16*  Xb    = (bf16*)carve((size_t)B * D * 2);
  bf16*  W1T   = (bf16*)carve((size_t)3 * R * D * 2);
  bf16*  W2T   = (bf16*)carve((size_t)3 * D * R * 2);
  bf16*  Tb    = (bf16*)carve((size_t)NTP * D * 2);
  bf16*  H     = (bf16*)carve((size_t)B * R * 2);
  bf16*  Fb    = (bf16*)carve((size_t)B * D * 2);

  hist_k<<<B / 256, 256, 0, stream>>>(lab, bhist);
  scan_k<<<1, 256, 0, stream>>>(bhist, boff, meta);
  scatter2_k<<<B / 256, 256, 0, stream>>>(lab, boff, perm);

  cvt_all_k<<<4096, 256, 0, stream>>>(x, W1, W2, text, Xb, W1T, W2T, Tb);

  // GEMM1: H = relu(Xb[perm] @ W1T[dom]^T)  — flat grid 8 XCD x 48 dm x 2 n = 768
  gemm_bt<true, 0, 2><<<768, 256, 0, stream>>>(
      Xb, W1T, H, perm, meta, R, D, R, R, nullptr, nullptr);
  // GEMM2: Fb[crow] = 0.2*relu(H @ W2T^T) + 0.8*Xb[crow]; ssp partials — 8 x 48 x 8 = 3072
  gemm_bt<false, 1, 8><<<3072, 256, 0, stream>>>(
      H, W2T, Fb, perm, meta, D, R, D, D, Xb, ssp);
  // GEMM3: out = exp(ls) * rinv[row] * (Fb @ Tb^T); rinv computed in-kernel from ssp
  gemm3_occ<<<1024, 256, 81920, stream>>>(Fb, Tb, out, lsc, ssp);
}

// Round 10
// 160.449 us; speedup vs baseline: 1.5078x; 1.0120x over previous
//
#include <hip/hip_runtime.h>
#include <hip/hip_bf16.h>
#include <math.h>

using bf16 = __hip_bfloat16;
typedef __attribute__((ext_vector_type(8))) short bf16x8;
typedef __attribute__((ext_vector_type(4))) float f32x4;
typedef __attribute__((ext_vector_type(4))) unsigned short us4;

#define GAS __attribute__((address_space(1)))
#define LAS __attribute__((address_space(3)))

__device__ __forceinline__ void gload_lds16(const bf16* g, bf16* lds) {
  __builtin_amdgcn_global_load_lds((const GAS void*)g, (LAS void*)lds, 16, 0, 0);
}
__device__ __forceinline__ float b2f(unsigned short u) {
  union { unsigned short s; bf16 b; } x; x.s = u; return __bfloat162float(x.b);
}

// ---------------- compaction (atomic-free, stable => deterministic) ----------------
__global__ __launch_bounds__(256) void hist_k(const int* __restrict__ lab,
                                              int* __restrict__ blockHist) {
  const int blk = blockIdx.x, t = threadIdx.x;
  const int lane = t & 63, w = t >> 6;
  const int d = lab[blk * 256 + t];
  __shared__ int wc[4][3];
#pragma unroll
  for (int dd = 0; dd < 3; ++dd) {
    unsigned long long m = __ballot(d == dd);
    if (lane == 0) wc[w][dd] = __popcll(m);
  }
  __syncthreads();
  if (t < 3) blockHist[blk * 3 + t] = wc[0][t] + wc[1][t] + wc[2][t] + wc[3][t];
}

__global__ __launch_bounds__(256) void scan_k(const int* __restrict__ blockHist,
                                              int* __restrict__ blockOff,
                                              int* __restrict__ meta) {
  __shared__ int h[64][3];
  __shared__ int tot[3];
  const int t = threadIdx.x;
  if (t < 192) h[t / 3][t % 3] = blockHist[t];
  __syncthreads();
  if (t < 3) {
    int s = 0;
    for (int b = 0; b < 64; ++b) { int v = h[b][t]; h[b][t] = s; s += v; }
    tot[t] = s;
    meta[t] = s;
  }
  __syncthreads();
  if (t == 0) { meta[4] = 0; meta[5] = tot[0]; meta[6] = tot[0] + tot[1]; }
  if (t < 192) {
    int b = t / 3, d = t % 3;
    int base = (d == 0) ? 0 : (d == 1 ? tot[0] : tot[0] + tot[1]);
    blockOff[t] = base + h[b][d];
  }
}

// writes perm (rank->orig) AND iperm (orig->rank)
__global__ __launch_bounds__(256) void scatter2_k(const int* __restrict__ lab,
                                                  const int* __restrict__ blockOff,
                                                  int* __restrict__ perm,
                                                  int* __restrict__ iperm) {
  const int blk = blockIdx.x, t = threadIdx.x;
  const int lane = t & 63, w = t >> 6;
  const int i = blk * 256 + t;
  const int d = lab[i];
  __shared__ int wc[4][3];
  unsigned long long mymask = 0;
#pragma unroll
  for (int dd = 0; dd < 3; ++dd) {
    unsigned long long m = __ballot(d == dd);
    if (lane == 0) wc[w][dd] = __popcll(m);
    if (dd == d) mymask = m;
  }
  __syncthreads();
  int woff = 0;
  for (int ww = 0; ww < w; ++ww) woff += wc[ww][d];
  const unsigned long long lt = ((unsigned long long)1 << lane) - 1;
  const int rank = blockOff[blk * 3 + d] + woff + __popcll(mymask & lt);
  perm[rank] = i;
  iperm[i] = rank;
}

// -- merged conversions (grid-stride): x -> Xbc (COMPACTED rows) | W1^T | W2^T | text --
__global__ __launch_bounds__(256) void cvt_all_k(const float* __restrict__ x,
                                                 const float* __restrict__ W1,
                                                 const float* __restrict__ W2,
                                                 const float* __restrict__ txt,
                                                 const int* __restrict__ iperm,
                                                 bf16* __restrict__ Xbc,
                                                 bf16* __restrict__ W1T,
                                                 bf16* __restrict__ W2T,
                                                 bf16* __restrict__ Tb) {
  const int nx = 16384 * 1024 / 4;
  const int n1 = 3 * 256 * 1024;
  const int n2 = n1 + 3 * 1024 * 256;
  const int n3 = n2 + 1536 * 1024;
  const int total = nx + n3;
  for (int i = blockIdx.x * 256 + threadIdx.x; i < total; i += 4096 * 256) {
    if (i < nx) {
      const int row = i >> 8, c4 = i & 255;    // 256 float4-chunks per row
      float4 v = ((const float4*)x)[i];
      bf16 t[4] = {__float2bfloat16(v.x), __float2bfloat16(v.y),
                   __float2bfloat16(v.z), __float2bfloat16(v.w)};
      ((us4*)Xbc)[(size_t)iperm[row] * 256 + c4] = *(const us4*)t;   // 1KB/row contiguous
      continue;
    }
    int j = i - nx;
    if (j < n1) {
      int d = j >> 18, rem = j & 262143;
      int r = rem >> 10, k = rem & 1023;
      W1T[j] = __float2bfloat16(W1[(size_t)d * 262144 + (size_t)k * 256 + r]);
    } else if (j < n2) {
      int jj = j - n1;
      int d = jj >> 18, rem = jj & 262143;
      int n = rem >> 8, k = rem & 255;
      W2T[jj] = __float2bfloat16(W2[(size_t)d * 262144 + (size_t)k * 1024 + n]);
    } else {
      int jj = j - n2;
      Tb[jj] = (jj < 1380 * 1024) ? __float2bfloat16(txt[jj]) : __float2bfloat16(0.f);
    }
  }
}

// -------- 128^2 2-phase GEMM for GEMM1/GEMM2 — fully DENSE (compacted rows) --------
// Flat grid, XCD-interleaved: xcd=bid&7, n=seq%NBLK, dm=xcd+8*(seq/NBLK), d=dm>>7, m=dm&127.
// All NBLK n-panels of one (d,m) on one XCD -> A/H panel L2-resident.
// EPI=0: C=relu(acc)->bf16 dense (GEMM1).  EPI=1: g=0.2*relu(acc)+0.8*Xbc (dense),
// dense Fbc write, ssp[n][compact_row] (one writer => deterministic).
template <int EPI, int NBLK>
__global__ __launch_bounds__(256) void gemm_bt(
    const bf16* __restrict__ A, const bf16* __restrict__ BT, bf16* __restrict__ Cv,
    const int* __restrict__ meta, int N, int K, int ldc, int Nvalid,
    const bf16* __restrict__ xb, float* __restrict__ ssp) {
  const int bid = blockIdx.x;
  const int xcd = bid & 7;
  const int seq = bid >> 3;
  const int nblkidx = seq % NBLK;
  const int dm = xcd + 8 * (seq / NBLK);
  const int dom = dm >> 7;
  const int mblk = dm & 127;

  const int cnt = meta[dom];
  const int base = meta[4 + dom];
  BT += (size_t)dom * N * K;

  const int m0 = mblk * 128;
  if (m0 >= cnt) return;
  const int n0 = nblkidx * 128;

  __shared__ bf16 sA[2][128][32];
  __shared__ bf16 sB[2][128][32];

  const int tid = threadIdx.x;
  const int wid = tid >> 6;
  const int lane = tid & 63;

  const int srow = (wid << 4) + (lane >> 2);
  const int skoff = (((lane & 3) ^ ((lane >> 2) & 3)) << 3);

  int p0 = m0 + srow;       if (p0 > cnt - 1) p0 = cnt - 1;
  int p1 = m0 + srow + 64;  if (p1 > cnt - 1) p1 = cnt - 1;
  const bf16* a0 = A + (size_t)(base + p0) * K + skoff;
  const bf16* a1 = A + (size_t)(base + p1) * K + skoff;
  const bf16* b0 = BT + (size_t)(n0 + srow) * K + skoff;
  const bf16* b1 = BT + (size_t)(n0 + srow + 64) * K + skoff;

  const int fr = lane & 15;
  const int fq = lane >> 4;
  const int rchunk = (fq ^ (fr & 3)) << 3;

  f32x4 acc[4][4];
#pragma unroll
  for (int m = 0; m < 4; ++m)
#pragma unroll
    for (int n = 0; n < 4; ++n) acc[m][n] = (f32x4){0.f, 0.f, 0.f, 0.f};

  const int nk = K >> 5;
  auto stage = [&](int buf, int kt) {
    gload_lds16(a0 + kt * 32, &sA[buf][wid * 16][0]);
    gload_lds16(a1 + kt * 32, &sA[buf][wid * 16 + 64][0]);
    gload_lds16(b0 + kt * 32, &sB[buf][wid * 16][0]);
    gload_lds16(b1 + kt * 32, &sB[buf][wid * 16 + 64][0]);
  };

  stage(0, 0);
  __syncthreads();
  const int wr = wid >> 1, wc = wid & 1;
  for (int kt = 0; kt < nk; ++kt) {
    const int cur = kt & 1;
    if (kt + 1 < nk) stage(cur ^ 1, kt + 1);
    bf16x8 af[4], bfr[4];
#pragma unroll
    for (int m = 0; m < 4; ++m)
      af[m] = *(const bf16x8*)&sA[cur][wr * 64 + m * 16 + fr][rchunk];
#pragma unroll
    for (int n = 0; n < 4; ++n)
      bfr[n] = *(const bf16x8*)&sB[cur][wc * 64 + n * 16 + fr][rchunk];
#pragma unroll
    for (int m = 0; m < 4; ++m)
#pragma unroll
      for (int n = 0; n < 4; ++n)
        acc[m][n] = __builtin_amdgcn_mfma_f32_16x16x32_bf16(af[m], bfr[n], acc[m][n], 0, 0, 0);
    __syncthreads();
  }

  if (EPI == 0) {
#pragma unroll
    for (int m = 0; m < 4; ++m) {
#pragma unroll
      for (int r = 0; r < 4; ++r) {
        const int p = m0 + wr * 64 + m * 16 + fq * 4 + r;
        if (p < cnt) {
          const size_t crow = (size_t)(base + p);
#pragma unroll
          for (int n = 0; n < 4; ++n) {
            const int col = n0 + wc * 64 + n * 16 + fr;
            if (col < Nvalid)
              Cv[crow * (size_t)ldc + col] = __float2bfloat16(fmaxf(acc[m][n][r], 0.f));
          }
        }
      }
    }
  } else {
    __shared__ float ssred[128][2];
#pragma unroll
    for (int m = 0; m < 4; ++m) {
#pragma unroll
      for (int r = 0; r < 4; ++r) {
        const int lr = wr * 64 + m * 16 + fq * 4 + r;
        const int p = m0 + lr;
        float rowss = 0.f;
        if (p < cnt) {
          const size_t crow = (size_t)(base + p);
#pragma unroll
          for (int n = 0; n < 4; ++n) {
            const int col = n0 + wc * 64 + n * 16 + fr;
            const float g = 0.2f * fmaxf(acc[m][n][r], 0.f) +
                            0.8f * b2f(*(const unsigned short*)&xb[crow * 1024 + col]);
            Cv[crow * (size_t)ldc + col] = __float2bfloat16(g);
            rowss += g * g;
          }
        }
        rowss += __shfl_xor(rowss, 1, 16);
        rowss += __shfl_xor(rowss, 2, 16);
        rowss += __shfl_xor(rowss, 4, 16);
        rowss += __shfl_xor(rowss, 8, 16);
        if (fr == 0) ssred[lr][wc] = rowss;
      }
    }
    __syncthreads();
    if (tid < 128) {
      const int p = m0 + tid;
      if (p < cnt)
        ssp[(size_t)nblkidx * 16384 + base + p] = ssred[tid][0] + ssred[tid][1];
    }
  }
}

// ============ GEMM3: 128x192, BK=64, 4 waves, 80KB LDS -> 2 blocks/CU ============
// Dense compact A; out rows scattered via perm (f32: 16 lanes x 4B = full 64B lines).
// rinv computed in-kernel from ssp (compact index).
__global__ __launch_bounds__(256, 2) void gemm3_occ(
    const bf16* __restrict__ A, const bf16* __restrict__ BT,
    float* __restrict__ C, const float* __restrict__ scale_ptr,
    const float* __restrict__ ssp, const int* __restrict__ perm) {
  extern __shared__ bf16 smem[];
  bf16* sA0 = smem;            // [2][128][64] = 32KB
  bf16* sB0 = smem + 16384;    // [2][192][64] = 48KB

  const int tid = threadIdx.x;
  const int lane = tid & 63, wid = tid >> 6;
  const int wr = wid >> 1, wc = wid & 1;     // 2x2; wave C = 64x96
  const int fr = lane & 15, fq = lane >> 4;

  const int bid = blockIdx.x;
  const int x = bid & 7, seq = bid >> 3;     // seq 0..127
  const int mb = x * 16 + (seq >> 3), nb = seq & 7;
  const int m0 = mb << 7, n0 = nb * 192;

  auto STAGE = [&](int t) {     // A 4 + B 6 loads/thread
    const int s = t & 1, koff = t << 6;
    bf16* da = sA0 + (s << 13);
#pragma unroll
    for (int L = 0; L < 4; ++L) {
      const int idx = (L << 8) + tid;
      const int r = idx >> 3, c = idx & 7;
      gload_lds16(A + (size_t)(m0 + r) * 1024 + koff + ((c ^ (r & 7)) << 3),
                  da + ((idx & ~63) << 3));
    }
    bf16* db = sB0 + s * 12288;
#pragma unroll
    for (int L = 0; L < 6; ++L) {
      const int idx = (L << 8) + tid;
      const int r = idx >> 3, c = idx & 7;
      gload_lds16(BT + (size_t)(n0 + r) * 1024 + koff + ((c ^ (r & 7)) << 3),
                  db + ((idx & ~63) << 3));
    }
  };
  auto LDA = [&](int s, int kk, bf16x8* dst) {
    const bf16* base = sA0 + (s << 13);
#pragma unroll
    for (int m = 0; m < 4; ++m) {
      const int row = (wr << 6) + (m << 4) + fr;
      dst[m] = *(const bf16x8*)(base + (row << 6) + ((((kk << 2) + fq) ^ (fr & 7)) << 3));
    }
  };
  auto LDB = [&](int s, int kk, bf16x8* dst) {
    const bf16* base = sB0 + s * 12288;
#pragma unroll
    for (int n = 0; n < 6; ++n) {
      const int row = wc * 96 + (n << 4) + fr;
      dst[n] = *(const bf16x8*)(base + (row << 6) + ((((kk << 2) + fq) ^ (fr & 7)) << 3));
    }
  };

  f32x4 acc[4][6];
#pragma unroll
  for (int m = 0; m < 4; ++m)
#pragma unroll
    for (int n = 0; n < 6; ++n) acc[m][n] = (f32x4){0.f, 0.f, 0.f, 0.f};

  STAGE(0);
  __syncthreads();
  const int nt = 16;
  for (int t = 0; t < nt; ++t) {
    const int s = t & 1;
    if (t + 1 < nt) STAGE(t + 1);
    bf16x8 a0[4], a1[4], b0[6], b1[6];
    LDA(s, 0, a0); LDB(s, 0, b0);
    LDA(s, 1, a1); LDB(s, 1, b1);
#pragma unroll
    for (int m = 0; m < 4; ++m)
#pragma unroll
      for (int n = 0; n < 6; ++n)
        acc[m][n] = __builtin_amdgcn_mfma_f32_16x16x32_bf16(a0[m], b0[n], acc[m][n], 0, 0, 0);
#pragma unroll
    for (int m = 0; m < 4; ++m)
#pragma unroll
      for (int n = 0; n < 6; ++n)
        acc[m][n] = __builtin_amdgcn_mfma_f32_16x16x32_bf16(a1[m], b1[n], acc[m][n], 0, 0, 0);
    __syncthreads();
  }

  // in-kernel rinv + perm for this block's 128 rows
  float* rlds = (float*)smem;                       // 512 B
  int*   plds = (int*)((char*)smem + 512);          // 512 B
  if (tid < 128) {
    float s = 0.f;
#pragma unroll
    for (int b = 0; b < 8; ++b) s += ssp[b * 16384 + m0 + tid];
    rlds[tid] = rsqrtf(s);
    plds[tid] = perm[m0 + tid];
  }
  __syncthreads();

  const float sc = expf(*scale_ptr);
#pragma unroll
  for (int m = 0; m < 4; ++m) {
    const int lrow = (wr << 6) + (m << 4) + (fq << 2);
#pragma unroll
    for (int r = 0; r < 4; ++r) {
      const float rv = sc * rlds[lrow + r];
      const size_t orow = (size_t)plds[lrow + r];
#pragma unroll
      for (int n = 0; n < 6; ++n) {
        const int gcol = n0 + wc * 96 + (n << 4) + fr;
        if (gcol < 1380) C[orow * 1380 + gcol] = acc[m][n][r] * rv;
      }
    }
  }
}

extern "C" void kernel_launch(void* const* d_in, const int* in_sizes, int n_in,
                              void* d_out, int out_size, void* d_ws, size_t ws_size,
                              hipStream_t stream) {
  (void)in_sizes; (void)n_in; (void)out_size; (void)ws_size;
  const float* x    = (const float*)d_in[0];
  const int*   lab  = (const int*)d_in[1];
  const float* W1   = (const float*)d_in[2];
  const float* W2   = (const float*)d_in[3];
  const float* text = (const float*)d_in[4];
  const float* lsc  = (const float*)d_in[5];
  float* out = (float*)d_out;

  const int B = 16384, D = 1024, R = 256, NTP = 1536;

  char* p = (char*)d_ws;
  auto carve = [&](size_t bytes) {
    char* r = p;
    p += (bytes + 255) & ~(size_t)255;
    return r;
  };
  int*   meta  = (int*)carve(64);
  int*   bhist = (int*)carve(64 * 3 * 4);
  int*   boff  = (int*)carve(64 * 3 * 4);
  int*   perm  = (int*)carve((size_t)B * 4);
  int*   iperm = (int*)carve((size_t)B * 4);
  float* ssp   = (float*)carve((size_t)8 * B * 4);
  bf16*  Xbc   = (bf16*)carve((size_t)B * D * 2);
  bf16*  W1T   = (bf16*)carve((size_t)3 * R * D * 2);
  bf16*  W2T   = (bf16*)carve((size_t)3 * D * R * 2);
  bf16*  Tb    = (bf16*)carve((size_t)NTP * D * 2);
  bf16*  H     = (bf16*)carve((size_t)B * R * 2);
  bf16*  Fbc   = (bf16*)carve((size_t)B * D * 2);

  hist_k<<<B / 256, 256, 0, stream>>>(lab, bhist);
  scan_k<<<1, 256, 0, stream>>>(bhist, boff, meta);
  scatter2_k<<<B / 256, 256, 0, stream>>>(lab, boff, perm, iperm);

  cvt_all_k<<<4096, 256, 0, stream>>>(x, W1, W2, text, iperm, Xbc, W1T, W2T, Tb);

  // GEMM1: H = relu(Xbc @ W1T[dom]^T), dense — 8 xcd x 48 dm x 2 n = 768
  gemm_bt<0, 2><<<768, 256, 0, stream>>>(
      Xbc, W1T, H, meta, R, D, R, R, nullptr, nullptr);
  // GEMM2: Fbc = 0.2*relu(H @ W2T^T) + 0.8*Xbc, dense; ssp partials — 3072
  gemm_bt<1, 8><<<3072, 256, 0, stream>>>(
      H, W2T, Fbc, meta, D, R, D, D, Xbc, ssp);
  // GEMM3: out[perm[row]] = exp(ls) * rinv[row] * (Fbc @ Tb^T)
  gemm3_occ<<<1024, 256, 81920, stream>>>(Fbc, Tb, out, lsc, ssp, perm);
}